// Round 4
// baseline (768.036 us; speedup 1.0000x reference)
//
#include <hip/hip_runtime.h>

typedef unsigned short u16;
typedef unsigned int u32;
typedef __bf16 bf16x8 __attribute__((ext_vector_type(8)));
typedef float f32x4 __attribute__((ext_vector_type(4)));

#define NN 10000
#define EE 160000
#define MPAD 10048   // 157 * 64

__device__ inline float b2f(u16 u) {
    return __uint_as_float(((u32)u) << 16);
}
__device__ inline u16 f2b(float f) {
    u32 u = __float_as_uint(f);
    u32 r = (u + 0x7fffu + ((u >> 16) & 1u)) >> 16;   // RNE
    return (u16)r;
}
__device__ inline float gelu_f(float x) {
    return 0.5f * x * (1.0f + erff(x * 0.70710678118654752f));
}

// ---------------- dtype detect: flag=1 if float inputs are f32, 0 if bf16 ----
__global__ __launch_bounds__(256) void k_detect(const u16* __restrict__ x, int* __restrict__ flag) {
    __shared__ int red[256];
    int t = threadIdx.x;
    int c = 0;
    for (int k = 0; k < 64; k++) {
        u16 u = x[t * 64 + k];
        if (((u >> 7) & 0xFF) == 0xFF) c++;
    }
    red[t] = c;
    __syncthreads();
    for (int off = 128; off; off >>= 1) {
        if (t < off) red[t] += red[t + off];
        __syncthreads();
    }
    if (t == 0) *flag = (red[0] >= 8) ? 1 : 0;
}

// generic small-tensor convert-to-bf16 (src is f32 if *flag else bf16)
__global__ __launch_bounds__(256) void k_cvt(const void* __restrict__ src, u16* __restrict__ dst,
                                             int n, const int* __restrict__ flag) {
    int i = blockIdx.x * 256 + threadIdx.x;
    if (i >= n) return;
    if (*flag) dst[i] = f2b(((const float*)src)[i]);
    else       dst[i] = ((const u16*)src)[i];
}

// ---------------- CSR build ----------------
__global__ __launch_bounds__(256) void k_count(const int* __restrict__ dst, int* __restrict__ cnt) {
    int e = blockIdx.x * 256 + threadIdx.x;
    if (e < EE) atomicAdd(&cnt[dst[e]], 1);
}

__global__ __launch_bounds__(256) void k_scan(const int* __restrict__ cnt, int* __restrict__ rowptr,
                                              int* __restrict__ cursor, float* __restrict__ dinv) {
    __shared__ int part[256];
    const int t = threadIdx.x;
    const int CH = 40;                    // 256*40 = 10240 >= NN
    int base = t * CH;
    int ssum = 0;
    for (int k = 0; k < CH; k++) { int i = base + k; if (i < NN) ssum += cnt[i]; }
    part[t] = ssum;
    __syncthreads();
    for (int off = 1; off < 256; off <<= 1) {
        int v = (t >= off) ? part[t - off] : 0;
        __syncthreads();
        part[t] += v;
        __syncthreads();
    }
    int run = part[t] - ssum;             // exclusive prefix
    for (int k = 0; k < CH; k++) {
        int i = base + k;
        if (i < NN) {
            rowptr[i] = run; cursor[i] = run;
            int c = cnt[i];
            dinv[i] = rsqrtf((float)(c + 1));   // self loop adds 1, deg always > 0
            run += c;
        }
    }
    if (t == 255) rowptr[NN] = run;
}

__global__ __launch_bounds__(256) void k_fill(const int* __restrict__ src, const int* __restrict__ dst,
                                              int* __restrict__ cursor, int* __restrict__ cols,
                                              float* __restrict__ vals, const float* __restrict__ dinv) {
    int e = blockIdx.x * 256 + threadIdx.x;
    if (e < EE) {
        int s = src[e], d = dst[e];
        int pos = atomicAdd(&cursor[d], 1);
        cols[pos] = s;
        vals[pos] = dinv[s] * dinv[d];
    }
}

// ---------------- input pad / weight transpose (dtype-adaptive) ----------------
__global__ __launch_bounds__(256) void k_padx(const void* __restrict__ x, u16* __restrict__ xp,
                                              const int* __restrict__ flag) {
    int idx = blockIdx.x * 256 + threadIdx.x;
    if (idx >= MPAD * 96) return;
    int r = idx / 96, c = idx - r * 96;
    u16 v = 0;
    if (r < NN && c < 84) {
        size_t o = (size_t)r * 84 + c;
        v = (*flag) ? f2b(((const float*)x)[o]) : ((const u16*)x)[o];
    }
    xp[idx] = v;
}

// dst[b][n][k] = (k<K) ? src[b][k][n] : 0   (dst row-stride Kp)
__global__ __launch_bounds__(256) void k_transpose(const void* __restrict__ src, u16* __restrict__ dst,
                                                   int Bn, int K, int Nc, int Kp,
                                                   const int* __restrict__ flag) {
    int idx = blockIdx.x * 256 + threadIdx.x;
    int tot = Bn * Nc * Kp;
    if (idx >= tot) return;
    int b = idx / (Nc * Kp);
    int rem = idx - b * Nc * Kp;
    int nr = rem / Kp;
    int k = rem - nr * Kp;
    u16 v = 0;
    if (k < K) {
        size_t o = (size_t)b * K * Nc + (size_t)k * Nc + nr;
        v = (*flag) ? f2b(((const float*)src)[o]) : ((const u16*)src)[o];
    }
    dst[idx] = v;
}

// ---------------- MFMA GEMM: C = act(A @ Bt^T + bias) ----------------
// A: [MPAD][K] bf16 row-major, Bt: [Nc][K] bf16 (pre-transposed weight)
// C: f32 (OUTF32) or bf16, row stride ldc, column offset col0. 64x64 tile, 4 waves 2x2.
template<int ACT, int OUTF32>
__global__ __launch_bounds__(256) void k_gemm(const u16* __restrict__ A, const u16* __restrict__ Bt,
                                              const u16* __restrict__ bias, void* __restrict__ Cv,
                                              int K, int ldc, int col0) {
    const int SK = 40;  // 32 + 8 pad -> 80B row stride (16B aligned, bank-spread)
    __shared__ u16 As[64 * SK];
    __shared__ u16 Bs[64 * SK];
    const int t = threadIdx.x;
    const int wave = t >> 6, lane = t & 63;
    const int wm = wave >> 1, wn = wave & 1;
    const int quad = lane >> 4, l16 = lane & 15;

    f32x4 acc[2][2];
#pragma unroll
    for (int a = 0; a < 2; a++)
#pragma unroll
        for (int b = 0; b < 2; b++)
#pragma unroll
            for (int r = 0; r < 4; r++) acc[a][b][r] = 0.f;

    const int srow = t >> 2, scol = (t & 3) << 3;   // 16B per thread, 64 rows x 32 cols
    const u16* Ap = A + (size_t)(blockIdx.x * 64 + srow) * K + scol;
    const u16* Bp = Bt + (size_t)(blockIdx.y * 64 + srow) * K + scol;
    u16* Asw = &As[srow * SK + scol];
    u16* Bsw = &Bs[srow * SK + scol];

    for (int k0 = 0; k0 < K; k0 += 32) {
        uint4 av = *(const uint4*)(Ap + k0);
        uint4 bv = *(const uint4*)(Bp + k0);
        __syncthreads();
        *(uint4*)Asw = av;
        *(uint4*)Bsw = bv;
        __syncthreads();
        bf16x8 a0 = *(const bf16x8*)(&As[(wm * 32 + l16) * SK + quad * 8]);
        bf16x8 a1 = *(const bf16x8*)(&As[(wm * 32 + 16 + l16) * SK + quad * 8]);
        bf16x8 b0 = *(const bf16x8*)(&Bs[(wn * 32 + l16) * SK + quad * 8]);
        bf16x8 b1 = *(const bf16x8*)(&Bs[(wn * 32 + 16 + l16) * SK + quad * 8]);
        acc[0][0] = __builtin_amdgcn_mfma_f32_16x16x32_bf16(a0, b0, acc[0][0], 0, 0, 0);
        acc[0][1] = __builtin_amdgcn_mfma_f32_16x16x32_bf16(a0, b1, acc[0][1], 0, 0, 0);
        acc[1][0] = __builtin_amdgcn_mfma_f32_16x16x32_bf16(a1, b0, acc[1][0], 0, 0, 0);
        acc[1][1] = __builtin_amdgcn_mfma_f32_16x16x32_bf16(a1, b1, acc[1][1], 0, 0, 0);
    }

#pragma unroll
    for (int tm = 0; tm < 2; tm++)
#pragma unroll
        for (int tn = 0; tn < 2; tn++)
#pragma unroll
            for (int r = 0; r < 4; r++) {
                int row = blockIdx.x * 64 + wm * 32 + tm * 16 + quad * 4 + r;
                int cl = wn * 32 + tn * 16 + l16;
                int colb = blockIdx.y * 64 + cl;
                float v = acc[tm][tn][r];
                if (bias) v += b2f(bias[colb]);
                if (ACT) v = gelu_f(v);
                size_t o = (size_t)row * ldc + col0 + colb;
                if (OUTF32) ((float*)Cv)[o] = v;
                else        ((u16*)Cv)[o] = f2b(v);
            }
}

// ---------------- propagation (D=256, one wave per node) ----------------
__global__ __launch_bounds__(64) void k_prop(const u16* __restrict__ hin, u16* __restrict__ hout,
                                             const int* __restrict__ rowptr, const int* __restrict__ cols,
                                             const float* __restrict__ vals, const float* __restrict__ dinv) {
    const int i = blockIdx.x;
    const int f0 = threadIdx.x * 4;
    float di = dinv[i];
    float sw = di * di;
    ushort4 sv = *(const ushort4*)(hin + (size_t)i * 256 + f0);
    float a0 = sw * b2f(sv.x), a1 = sw * b2f(sv.y), a2 = sw * b2f(sv.z), a3 = sw * b2f(sv.w);
    int s = rowptr[i], e = rowptr[i + 1];
    for (int q = s; q < e; q++) {
        int j = cols[q];
        float w = vals[q];
        ushort4 v = *(const ushort4*)(hin + (size_t)j * 256 + f0);
        a0 += w * b2f(v.x); a1 += w * b2f(v.y); a2 += w * b2f(v.z); a3 += w * b2f(v.w);
    }
    ushort4 o; o.x = f2b(a0); o.y = f2b(a1); o.z = f2b(a2); o.w = f2b(a3);
    *(ushort4*)(hout + (size_t)i * 256 + f0) = o;
}

// same, but writes into concat[:, col0:col0+256] (row stride 1024) with bias add
template<int OUTF32>
__global__ __launch_bounds__(64) void k_prop_out(const u16* __restrict__ hin, void* __restrict__ outc,
                                                 const int* __restrict__ rowptr, const int* __restrict__ cols,
                                                 const float* __restrict__ vals, const float* __restrict__ dinv,
                                                 const u16* __restrict__ bias, int col0) {
    const int i = blockIdx.x;
    const int f0 = threadIdx.x * 4;
    float di = dinv[i];
    float sw = di * di;
    ushort4 sv = *(const ushort4*)(hin + (size_t)i * 256 + f0);
    float a0 = sw * b2f(sv.x), a1 = sw * b2f(sv.y), a2 = sw * b2f(sv.z), a3 = sw * b2f(sv.w);
    int s = rowptr[i], e = rowptr[i + 1];
    for (int q = s; q < e; q++) {
        int j = cols[q];
        float w = vals[q];
        ushort4 v = *(const ushort4*)(hin + (size_t)j * 256 + f0);
        a0 += w * b2f(v.x); a1 += w * b2f(v.y); a2 += w * b2f(v.z); a3 += w * b2f(v.w);
    }
    a0 += b2f(bias[f0 + 0]); a1 += b2f(bias[f0 + 1]);
    a2 += b2f(bias[f0 + 2]); a3 += b2f(bias[f0 + 3]);
    size_t o = (size_t)i * 1024 + col0 + f0;
    if (OUTF32) {
        float4 v; v.x = a0; v.y = a1; v.z = a2; v.w = a3;
        *(float4*)((float*)outc + o) = v;
    } else {
        ushort4 v; v.x = f2b(a0); v.y = f2b(a1); v.z = f2b(a2); v.w = f2b(a3);
        *(ushort4*)((u16*)outc + o) = v;
    }
}

// ---------------- LayerNorm(1024) + gelu -> bf16 out ----------------
template<int INF32>
__global__ __launch_bounds__(256) void k_ln_gelu(const void* __restrict__ X, const u16* __restrict__ g,
                                                 const u16* __restrict__ b, u16* __restrict__ out) {
    __shared__ float red[256];
    const int row = blockIdx.x, t = threadIdx.x;
    float x0, x1, x2, x3;
    if (INF32) {
        float4 xv = *(const float4*)((const float*)X + (size_t)row * 1024 + t * 4);
        x0 = xv.x; x1 = xv.y; x2 = xv.z; x3 = xv.w;
    } else {
        ushort4 xv = *(const ushort4*)((const u16*)X + (size_t)row * 1024 + t * 4);
        x0 = b2f(xv.x); x1 = b2f(xv.y); x2 = b2f(xv.z); x3 = b2f(xv.w);
    }
    red[t] = x0 + x1 + x2 + x3;
    __syncthreads();
    for (int off = 128; off; off >>= 1) {
        if (t < off) red[t] += red[t + off];
        __syncthreads();
    }
    float mu = red[0] * (1.f / 1024.f);
    __syncthreads();
    float d0 = x0 - mu, d1 = x1 - mu, d2 = x2 - mu, d3 = x3 - mu;
    red[t] = d0 * d0 + d1 * d1 + d2 * d2 + d3 * d3;
    __syncthreads();
    for (int off = 128; off; off >>= 1) {
        if (t < off) red[t] += red[t + off];
        __syncthreads();
    }
    float rs = rsqrtf(red[0] * (1.f / 1024.f) + 1e-5f);
    int c = t * 4;
    ushort4 gv = *(const ushort4*)(g + c);
    ushort4 bv = *(const ushort4*)(b + c);
    float y0 = gelu_f(d0 * rs * b2f(gv.x) + b2f(bv.x));
    float y1 = gelu_f(d1 * rs * b2f(gv.y) + b2f(bv.y));
    float y2 = gelu_f(d2 * rs * b2f(gv.z) + b2f(bv.z));
    float y3 = gelu_f(d3 * rs * b2f(gv.w) + b2f(bv.w));
    ushort4 o; o.x = f2b(y0); o.y = f2b(y1); o.z = f2b(y2); o.w = f2b(y3);
    *(ushort4*)(out + (size_t)row * 1024 + c) = o;
}

// ---------------- final dot: out[i] = h[i,0:128] . w3 + b3  (f32 OUT) --------
__global__ __launch_bounds__(256) void k_final(const u16* __restrict__ h, const u16* __restrict__ w3,
                                               const u16* __restrict__ b3, float* __restrict__ out,
                                               float wsmb) {
    int gw = (blockIdx.x * 256 + threadIdx.x) >> 6;
    int lane = threadIdx.x & 63;
    if (gw >= NN) return;
    u32 hv = *(const u32*)(h + (size_t)gw * 128 + lane * 2);
    u32 wv = *(const u32*)(w3 + lane * 2);
    float s = b2f((u16)(hv & 0xffff)) * b2f((u16)(wv & 0xffff)) +
              b2f((u16)(hv >> 16)) * b2f((u16)(wv >> 16));
    for (int off = 32; off; off >>= 1) s += __shfl_down(s, off);
    if (lane == 0) {
        float r = s + b2f(b3[0]);
        if (!(r == r) || fabsf(r) > 1e30f) r = 1000.0f + wsmb;   // sentinel (never expected)
        out[gw] = r;
    }
}

// ---------------- schedule (templated on concat dtype) ----------------
struct Bufs {
    int *flag, *cnt, *rowptr, *cursor, *cols;
    float *dinv, *vals;
    u16 *xp, *winT, *w0T, *w12T, *w1T, *w2T;
    u16 *binC, *mb0C, *mb12C, *lngC, *lnbC, *b1C, *b2C, *w3C, *b3C;
    u16 *S1, *S2, *bufA;
    void *concat;
};

template<int CF32>
static void run_net(const Bufs& B, float* out, float wsmb, hipStream_t stream) {
    dim3 g4(MPAD / 64, 4);   // Nc = 256
    dim3 g2(MPAD / 64, 2);   // Nc = 128

    // zero pad rows (deterministic every call)
    hipMemsetAsync(B.S1 + (size_t)NN * 256, 0, (size_t)(MPAD - NN) * 256 * 2, stream);
    hipMemsetAsync(B.S2 + (size_t)NN * 256, 0, (size_t)(MPAD - NN) * 256 * 2, stream);
    hipMemsetAsync(B.bufA + (size_t)NN * 1024, 0, (size_t)(MPAD - NN) * 1024 * 2, stream);
    hipMemsetAsync((char*)B.concat + (size_t)NN * 1024 * (CF32 ? 4 : 2), 0,
                   (size_t)(MPAD - NN) * 1024 * (CF32 ? 4 : 2), stream);

    // input: h0 = gelu(xp @ winT^T + b_in) -> S1 [MPAD,256]
    k_gemm<1, 0><<<g4, 256, 0, stream>>>(B.xp, B.winT, B.binC, B.S1, 96, 256, 0);

    // ---- layer 0: propagate-then-GEMM, S1/S2 ping-pong ----
    k_gemm<0, CF32><<<g4, 256, 0, stream>>>(B.S1, B.w0T + 0 * 65536, B.mb0C + 0,   B.concat, 256, 1024, 0);
    k_prop<<<NN, 64, 0, stream>>>(B.S1, B.S2, B.rowptr, B.cols, B.vals, B.dinv);
    k_gemm<0, CF32><<<g4, 256, 0, stream>>>(B.S2, B.w0T + 1 * 65536, B.mb0C + 256, B.concat, 256, 1024, 256);
    k_prop<<<NN, 64, 0, stream>>>(B.S2, B.S1, B.rowptr, B.cols, B.vals, B.dinv);
    k_gemm<0, CF32><<<g4, 256, 0, stream>>>(B.S1, B.w0T + 2 * 65536, B.mb0C + 512, B.concat, 256, 1024, 512);
    k_prop<<<NN, 64, 0, stream>>>(B.S1, B.S2, B.rowptr, B.cols, B.vals, B.dinv);
    k_gemm<0, CF32><<<g4, 256, 0, stream>>>(B.S2, B.w0T + 3 * 65536, B.mb0C + 768, B.concat, 256, 1024, 768);
    k_ln_gelu<CF32><<<NN, 256, 0, stream>>>(B.concat, B.lngC + 0, B.lnbC + 0, B.bufA);

    // ---- layers 1,2: GEMM-then-propagate ( (A^p h)W = A^p (hW) ) ----
    for (int L = 0; L < 2; L++) {
        const u16* WT = B.w12T + (size_t)L * 4 * 256 * 1024;
        const u16* BB = B.mb12C + L * 4 * 256;
        k_gemm<0, CF32><<<g4, 256, 0, stream>>>(B.bufA, WT + 0 * 262144, BB + 0, B.concat, 1024, 1024, 0);
        k_gemm<0, 0><<<g4, 256, 0, stream>>>(B.bufA, WT + 1 * 262144, nullptr, B.S1, 1024, 256, 0);
        k_prop_out<CF32><<<NN, 64, 0, stream>>>(B.S1, B.concat, B.rowptr, B.cols, B.vals, B.dinv, BB + 256, 256);
        k_gemm<0, 0><<<g4, 256, 0, stream>>>(B.bufA, WT + 2 * 262144, nullptr, B.S1, 1024, 256, 0);
        k_prop<<<NN, 64, 0, stream>>>(B.S1, B.S2, B.rowptr, B.cols, B.vals, B.dinv);
        k_prop_out<CF32><<<NN, 64, 0, stream>>>(B.S2, B.concat, B.rowptr, B.cols, B.vals, B.dinv, BB + 512, 512);
        k_gemm<0, 0><<<g4, 256, 0, stream>>>(B.bufA, WT + 3 * 262144, nullptr, B.S1, 1024, 256, 0);
        k_prop<<<NN, 64, 0, stream>>>(B.S1, B.S2, B.rowptr, B.cols, B.vals, B.dinv);
        k_prop<<<NN, 64, 0, stream>>>(B.S2, B.S1, B.rowptr, B.cols, B.vals, B.dinv);
        k_prop_out<CF32><<<NN, 64, 0, stream>>>(B.S1, B.concat, B.rowptr, B.cols, B.vals, B.dinv, BB + 768, 768);
        k_ln_gelu<CF32><<<NN, 256, 0, stream>>>(B.concat, B.lngC + (L + 1) * 1024, B.lnbC + (L + 1) * 1024, B.bufA);
    }

    // ---- final MLP ----
    k_gemm<1, 0><<<g4, 256, 0, stream>>>(B.bufA, B.w1T, B.b1C, B.S1, 1024, 256, 0);
    k_gemm<1, 0><<<g2, 256, 0, stream>>>(B.S1, B.w2T, B.b2C, B.S2, 256, 128, 0);
    k_final<<<(NN + 3) / 4, 256, 0, stream>>>(B.S2, B.w3C, B.b3C, out, wsmb);
}

extern "C" void kernel_launch(void* const* d_in, const int* in_sizes, int n_in,
                              void* d_out, int out_size, void* d_ws, size_t ws_size,
                              hipStream_t stream) {
    (void)in_sizes; (void)n_in; (void)out_size;
    const void* x_r      = d_in[0];
    const int*  ei       = (const int*)d_in[1];
    float* out = (float*)d_out;

    char* p = (char*)d_ws;
    auto alloc = [&](size_t bytes) { char* q = p; p += (bytes + 255) & ~(size_t)255; return q; };
    Bufs B;
    B.flag   = (int*)alloc(4);
    B.cnt    = (int*)alloc(NN * 4);
    B.rowptr = (int*)alloc((NN + 1) * 4);
    B.cursor = (int*)alloc(NN * 4);
    B.dinv   = (float*)alloc(NN * 4);
    B.cols   = (int*)alloc(EE * 4);
    B.vals   = (float*)alloc(EE * 4);
    B.xp     = (u16*)alloc((size_t)MPAD * 96 * 2);
    B.winT   = (u16*)alloc(256 * 96 * 2);
    B.w0T    = (u16*)alloc((size_t)4 * 256 * 256 * 2);
    B.w12T   = (u16*)alloc((size_t)8 * 256 * 1024 * 2);
    B.w1T    = (u16*)alloc((size_t)256 * 1024 * 2);
    B.w2T    = (u16*)alloc((size_t)128 * 256 * 2);
    B.binC   = (u16*)alloc(256 * 2);
    B.mb0C   = (u16*)alloc(1024 * 2);
    B.mb12C  = (u16*)alloc(2048 * 2);
    B.lngC   = (u16*)alloc(3072 * 2);
    B.lnbC   = (u16*)alloc(3072 * 2);
    B.b1C    = (u16*)alloc(256 * 2);
    B.b2C    = (u16*)alloc(128 * 2);
    B.w3C    = (u16*)alloc(128 * 2);
    B.b3C    = (u16*)alloc(1 * 2);
    B.S1     = (u16*)alloc((size_t)MPAD * 256 * 2);
    B.S2     = (u16*)alloc((size_t)MPAD * 256 * 2);
    B.bufA   = (u16*)alloc((size_t)MPAD * 1024 * 2);
    // concat last: f32 if it fits, else bf16 (host branch on ws_size is
    // constant across calls -> graph-capture safe)
    size_t used = (size_t)(p - (char*)d_ws);
    bool cf32 = (ws_size - used) >= ((size_t)MPAD * 1024 * 4 + 4096);
    B.concat = (void*)alloc((size_t)MPAD * 1024 * (cf32 ? 4 : 2));

    const int* srcA = ei;
    const int* dstA = ei + EE;

    hipMemsetAsync(B.cnt, 0, NN * 4, stream);

    // dtype detect, then convert/stage all float tensors as bf16 in ws
    k_detect<<<1, 256, 0, stream>>>((const u16*)x_r, B.flag);
    k_padx<<<(MPAD * 96 + 255) / 256, 256, 0, stream>>>(x_r, B.xp, B.flag);
    k_transpose<<<(256 * 96 + 255) / 256, 256, 0, stream>>>(d_in[2], B.winT, 1, 84, 256, 96, B.flag);
    k_transpose<<<(4 * 256 * 256 + 255) / 256, 256, 0, stream>>>(d_in[4], B.w0T, 4, 256, 256, 256, B.flag);
    k_transpose<<<(8 * 256 * 1024 + 255) / 256, 256, 0, stream>>>(d_in[6], B.w12T, 8, 1024, 256, 1024, B.flag);
    k_transpose<<<(256 * 1024 + 255) / 256, 256, 0, stream>>>(d_in[10], B.w1T, 1, 1024, 256, 1024, B.flag);
    k_transpose<<<(128 * 256 + 255) / 256, 256, 0, stream>>>(d_in[12], B.w2T, 1, 256, 128, 256, B.flag);
    k_cvt<<<1, 256, 0, stream>>>(d_in[3],  B.binC, 256, B.flag);
    k_cvt<<<4, 256, 0, stream>>>(d_in[5],  B.mb0C, 1024, B.flag);
    k_cvt<<<8, 256, 0, stream>>>(d_in[7],  B.mb12C, 2048, B.flag);
    k_cvt<<<12, 256, 0, stream>>>(d_in[8], B.lngC, 3072, B.flag);
    k_cvt<<<12, 256, 0, stream>>>(d_in[9], B.lnbC, 3072, B.flag);
    k_cvt<<<1, 256, 0, stream>>>(d_in[11], B.b1C, 256, B.flag);
    k_cvt<<<1, 256, 0, stream>>>(d_in[13], B.b2C, 128, B.flag);
    k_cvt<<<1, 256, 0, stream>>>(d_in[14], B.w3C, 128, B.flag);
    k_cvt<<<1, 256, 0, stream>>>(d_in[15], B.b3C, 1, B.flag);

    // CSR build
    k_count<<<(EE + 255) / 256, 256, 0, stream>>>(dstA, B.cnt);
    k_scan<<<1, 256, 0, stream>>>(B.cnt, B.rowptr, B.cursor, B.dinv);
    k_fill<<<(EE + 255) / 256, 256, 0, stream>>>(srcA, dstA, B.cursor, B.cols, B.vals, B.dinv);

    float wsmb = (float)(ws_size >> 20);
    if (cf32) run_net<1>(B, out, wsmb, stream);
    else      run_net<0>(B, out, wsmb, stream);
}

// Round 5
// 596.576 us; speedup vs baseline: 1.2874x; 1.2874x over previous
//
#include <hip/hip_runtime.h>

typedef unsigned short u16;
typedef unsigned int u32;
typedef __bf16 bf16x8 __attribute__((ext_vector_type(8)));
typedef float f32x4 __attribute__((ext_vector_type(4)));

#define NN 10000
#define EE 160000
#define MPAD 10112   // 79 * 128

__device__ inline float b2f(u16 u) { return __uint_as_float(((u32)u) << 16); }
__device__ inline u16 f2b(float f) {
    u32 u = __float_as_uint(f);
    return (u16)((u + 0x7fffu + ((u >> 16) & 1u)) >> 16);   // RNE
}
__device__ inline float gelu_f(float x) {
    return 0.5f * x * (1.0f + erff(x * 0.70710678118654752f));
}
__device__ inline void load_lds16(const u16* g, u16* l) {
    __builtin_amdgcn_global_load_lds((const __attribute__((address_space(1))) u32*)g,
                                     (__attribute__((address_space(3))) u32*)l, 16, 0, 0);
}

// ---------------- CSR build ----------------
__global__ __launch_bounds__(256) void k_count(const int* __restrict__ dst, int* __restrict__ cnt) {
    int e = blockIdx.x * 256 + threadIdx.x;
    if (e < EE) atomicAdd(&cnt[dst[e]], 1);
}

__global__ __launch_bounds__(256) void k_scan(const int* __restrict__ cnt, int* __restrict__ rowptr,
                                              int* __restrict__ cursor, float* __restrict__ dinv) {
    __shared__ int part[256];
    const int t = threadIdx.x;
    const int CH = 40;
    int base = t * CH;
    int ssum = 0;
    for (int k = 0; k < CH; k++) { int i = base + k; if (i < NN) ssum += cnt[i]; }
    part[t] = ssum;
    __syncthreads();
    for (int off = 1; off < 256; off <<= 1) {
        int v = (t >= off) ? part[t - off] : 0;
        __syncthreads();
        part[t] += v;
        __syncthreads();
    }
    int run = part[t] - ssum;
    for (int k = 0; k < CH; k++) {
        int i = base + k;
        if (i < NN) {
            rowptr[i] = run; cursor[i] = run;
            int c = cnt[i];
            dinv[i] = rsqrtf((float)(c + 1));
            run += c;
        }
    }
    if (t == 255) rowptr[NN] = run;
}

__global__ __launch_bounds__(256) void k_fill(const int* __restrict__ src, const int* __restrict__ dst,
                                              int* __restrict__ cursor, int* __restrict__ cols,
                                              float* __restrict__ vals, const float* __restrict__ dinv) {
    int e = blockIdx.x * 256 + threadIdx.x;
    if (e < EE) {
        int s = src[e], d = dst[e];
        int pos = atomicAdd(&cursor[d], 1);
        cols[pos] = s;
        vals[pos] = dinv[s] * dinv[d];
    }
}

// ---------------- ingest (f32 inputs -> bf16 ws copies) ----------------
__global__ __launch_bounds__(256) void k_padx(const float* __restrict__ x, u16* __restrict__ xp) {
    int idx = blockIdx.x * 256 + threadIdx.x;
    if (idx >= MPAD * 96) return;
    int r = idx / 96, c = idx - r * 96;
    u16 v = 0;
    if (r < NN && c < 84) v = f2b(x[(size_t)r * 84 + c]);
    xp[idx] = v;
}

struct TransSrcs { const float *w_in, *mh_w0, *mh_w12, *w1, *w2; };
// all weight transposes in one kernel; dst = wbuf (contiguous)
__global__ __launch_bounds__(256) void k_trans_all(TransSrcs S, u16* __restrict__ wbuf) {
    int idx = blockIdx.x * 256 + threadIdx.x;
    const float* src; int local, Kp, K, Nc;
    if (idx < 24576)        { src = S.w_in;   local = idx;           Kp = 96;   K = 84;   Nc = 256; }
    else if (idx < 286720)  { src = S.mh_w0;  local = idx - 24576;   Kp = 256;  K = 256;  Nc = 256; }
    else if (idx < 2383872) { src = S.mh_w12; local = idx - 286720;  Kp = 1024; K = 1024; Nc = 256; }
    else if (idx < 2646016) { src = S.w1;     local = idx - 2383872; Kp = 1024; K = 1024; Nc = 256; }
    else if (idx < 2678784) { src = S.w2;     local = idx - 2646016; Kp = 256;  K = 256;  Nc = 128; }
    else return;
    int b   = local / (Nc * Kp);
    int rem = local - b * Nc * Kp;
    int nr  = rem / Kp;
    int k   = rem - nr * Kp;
    u16 v = 0;
    if (k < K) v = f2b(src[(size_t)b * K * Nc + (size_t)k * Nc + nr]);
    wbuf[idx] = v;
}

struct CvtSrcs { const float *b_in, *mh_b0, *mh_b12, *ln_g, *ln_b, *b1, *b2, *w3, *b3; };
// offsets: b_in 0, mh_b0 256, mh_b12 1280, ln_g 3328, ln_b 6400, b1 9472, b2 9728, w3 9856, b3 9984
__global__ __launch_bounds__(256) void k_cvt_all(CvtSrcs S, u16* __restrict__ dst) {
    int i = blockIdx.x * 256 + threadIdx.x;
    const float* s; int base;
    if (i < 256)       { s = S.b_in;   base = 0; }
    else if (i < 1280) { s = S.mh_b0;  base = 256; }
    else if (i < 3328) { s = S.mh_b12; base = 1280; }
    else if (i < 6400) { s = S.ln_g;   base = 3328; }
    else if (i < 9472) { s = S.ln_b;   base = 6400; }
    else if (i < 9728) { s = S.b1;     base = 9472; }
    else if (i < 9856) { s = S.b2;     base = 9728; }
    else if (i < 9984) { s = S.w3;     base = 9856; }
    else if (i < 9985) { s = S.b3;     base = 9984; }
    else return;
    dst[i] = f2b(s[i - base]);
}

// ---------------- 128x128 MFMA GEMM, global_load_lds staging ----------------
// A:[M][K] bf16, Bt:[N][K] bf16. EPI 0: bf16 C (+bias, opt gelu). 1: f32 C (+bias).
// 2: split — col<256 -> f32 concat(stride 1024)+bias ; col>=256 -> bf16 Z (stride 768).
// BATCH: blockIdx.z selects A in {A0..A3}, offsets Bt/bias/col0 by z*256-block.
template<int ACT, int EPI, int BATCH>
__global__ __launch_bounds__(256) void k_gemm128(const u16* __restrict__ A0, const u16* __restrict__ A1,
                                                 const u16* __restrict__ A2, const u16* __restrict__ A3,
                                                 const u16* __restrict__ Bt, const u16* __restrict__ bias,
                                                 void* __restrict__ C, u16* __restrict__ Z,
                                                 int K, int ldc, int col0) {
    __shared__ __align__(16) u16 As[128 * 32];
    __shared__ __align__(16) u16 Bs[128 * 32];
    const u16* A = A0;
    if (BATCH) {
        int z = blockIdx.z;
        if (z == 1) A = A1; else if (z == 2) A = A2; else if (z == 3) A = A3;
        Bt   += (size_t)z * 256 * K;
        bias += z * 256;
        col0 += z * 256;
    }
    const int t = threadIdx.x;
    const int wv = t >> 6, lane = t & 63;
    const int wm = wv >> 1, wn = wv & 1;
    const int quad = lane >> 4, l16 = lane & 15;
    const int tileM = blockIdx.x * 128, tileN = blockIdx.y * 128;

    f32x4 acc[4][4] = {};

    const int rch = lane >> 2;          // row within 16-row chunk
    const int c8  = (lane & 3) * 8;     // col offset (elements)
    const int ch0 = wv * 2, ch1 = wv * 2 + 1;
    const u16* ga0 = A  + (size_t)(tileM + ch0 * 16 + rch) * K + c8;
    const u16* ga1 = A  + (size_t)(tileM + ch1 * 16 + rch) * K + c8;
    const u16* gb0 = Bt + (size_t)(tileN + ch0 * 16 + rch) * K + c8;
    const u16* gb1 = Bt + (size_t)(tileN + ch1 * 16 + rch) * K + c8;
    u16* la0 = &As[ch0 * 512 + lane * 8];
    u16* la1 = &As[ch1 * 512 + lane * 8];
    u16* lb0 = &Bs[ch0 * 512 + lane * 8];
    u16* lb1 = &Bs[ch1 * 512 + lane * 8];

    for (int k0 = 0; k0 < K; k0 += 32) {
        __syncthreads();
        load_lds16(ga0 + k0, la0);
        load_lds16(ga1 + k0, la1);
        load_lds16(gb0 + k0, lb0);
        load_lds16(gb1 + k0, lb1);
        __syncthreads();
        bf16x8 af[4], bfr[4];
#pragma unroll
        for (int tm = 0; tm < 4; tm++)
            af[tm] = *(const bf16x8*)&As[(wm * 64 + tm * 16 + l16) * 32 + quad * 8];
#pragma unroll
        for (int tn = 0; tn < 4; tn++)
            bfr[tn] = *(const bf16x8*)&Bs[(wn * 64 + tn * 16 + l16) * 32 + quad * 8];
#pragma unroll
        for (int tm = 0; tm < 4; tm++)
#pragma unroll
            for (int tn = 0; tn < 4; tn++)
                acc[tm][tn] = __builtin_amdgcn_mfma_f32_16x16x32_bf16(af[tm], bfr[tn], acc[tm][tn], 0, 0, 0);
    }

#pragma unroll
    for (int tm = 0; tm < 4; tm++)
#pragma unroll
        for (int tn = 0; tn < 4; tn++)
#pragma unroll
            for (int r = 0; r < 4; r++) {
                int row = tileM + wm * 64 + tm * 16 + quad * 4 + r;
                int col = tileN + wn * 64 + tn * 16 + l16;
                float v = acc[tm][tn][r];
                if (EPI == 2) {
                    if (col < 256) ((float*)C)[(size_t)row * 1024 + col] = v + b2f(bias[col]);
                    else           Z[(size_t)row * 768 + (col - 256)] = f2b(v);
                } else {
                    v += b2f(bias[col]);
                    if (ACT) v = gelu_f(v);
                    size_t o = (size_t)row * ldc + col0 + col;
                    if (EPI == 1) ((float*)C)[o] = v;
                    else          ((u16*)C)[o] = f2b(v);
                }
            }
}

// ---------------- wide propagation ----------------
// hin: [.., W] bf16 (W = 256*G). One wave per (node, 256-col group).
// group 0 (if F32OUT0): -> concat f32 [node][1024] at col0, + bias.
// other groups:         -> out2 bf16, stride W - 256*F32OUT0, col (g-F32OUT0)*256.
// lanes split into two 32-lane halves processing even/odd edges (2 gathers in flight).
template<int F32OUT0>
__global__ __launch_bounds__(256) void k_propw(const u16* __restrict__ hin, int W, int G,
                                               const int* __restrict__ rowptr, const int* __restrict__ cols,
                                               const float* __restrict__ vals, const float* __restrict__ dinv,
                                               float* __restrict__ concat, const u16* __restrict__ bias,
                                               int col0, u16* __restrict__ out2) {
    int unit = blockIdx.x * 4 + (threadIdx.x >> 6);
    if (unit >= NN * G) return;
    int node = unit / G, g = unit - node * G;
    int lane = threadIdx.x & 63;
    int half = lane >> 5, fl = lane & 31;
    const u16* base = hin + g * 256 + fl * 8;
    float a0 = 0, a1 = 0, a2 = 0, a3 = 0, a4 = 0, a5 = 0, a6 = 0, a7 = 0;
    int s = rowptr[node], e = rowptr[node + 1];
    for (int q = s + half; q < e; q += 2) {
        int j = cols[q];
        float w = vals[q];
        bf16x8 v = *(const bf16x8*)(base + (size_t)j * W);
        a0 += w * (float)v[0]; a1 += w * (float)v[1]; a2 += w * (float)v[2]; a3 += w * (float)v[3];
        a4 += w * (float)v[4]; a5 += w * (float)v[5]; a6 += w * (float)v[6]; a7 += w * (float)v[7];
    }
    a0 += __shfl_down(a0, 32); a1 += __shfl_down(a1, 32);
    a2 += __shfl_down(a2, 32); a3 += __shfl_down(a3, 32);
    a4 += __shfl_down(a4, 32); a5 += __shfl_down(a5, 32);
    a6 += __shfl_down(a6, 32); a7 += __shfl_down(a7, 32);
    if (half == 0) {
        float di = dinv[node], sw = di * di;
        bf16x8 sv = *(const bf16x8*)(base + (size_t)node * W);
        a0 += sw * (float)sv[0]; a1 += sw * (float)sv[1]; a2 += sw * (float)sv[2]; a3 += sw * (float)sv[3];
        a4 += sw * (float)sv[4]; a5 += sw * (float)sv[5]; a6 += sw * (float)sv[6]; a7 += sw * (float)sv[7];
        int f = fl * 8;
        if (F32OUT0 && g == 0) {
            float* o = concat + (size_t)node * 1024 + col0 + f;
            float4 v0, v1;
            v0.x = a0 + b2f(bias[f + 0]); v0.y = a1 + b2f(bias[f + 1]);
            v0.z = a2 + b2f(bias[f + 2]); v0.w = a3 + b2f(bias[f + 3]);
            v1.x = a4 + b2f(bias[f + 4]); v1.y = a5 + b2f(bias[f + 5]);
            v1.z = a6 + b2f(bias[f + 6]); v1.w = a7 + b2f(bias[f + 7]);
            *(float4*)o = v0;
            *(float4*)(o + 4) = v1;
        } else {
            int W2 = W - F32OUT0 * 256;
            u16* o = out2 + (size_t)node * W2 + (g - F32OUT0) * 256 + f;
            union { u16 u[8]; uint4 v; } pk;
            pk.u[0] = f2b(a0); pk.u[1] = f2b(a1); pk.u[2] = f2b(a2); pk.u[3] = f2b(a3);
            pk.u[4] = f2b(a4); pk.u[5] = f2b(a5); pk.u[6] = f2b(a6); pk.u[7] = f2b(a7);
            *(uint4*)o = pk.v;
        }
    }
}

// ---------------- LayerNorm(1024) + gelu, f32 in -> bf16 out ----------------
__global__ __launch_bounds__(256) void k_ln_gelu(const float* __restrict__ X, const u16* __restrict__ g,
                                                 const u16* __restrict__ b, u16* __restrict__ out) {
    __shared__ float red[256];
    const int row = blockIdx.x, t = threadIdx.x;
    float4 x = *(const float4*)(X + (size_t)row * 1024 + t * 4);
    red[t] = x.x + x.y + x.z + x.w;
    __syncthreads();
    for (int off = 128; off; off >>= 1) {
        if (t < off) red[t] += red[t + off];
        __syncthreads();
    }
    float mu = red[0] * (1.f / 1024.f);
    __syncthreads();
    float d0 = x.x - mu, d1 = x.y - mu, d2 = x.z - mu, d3 = x.w - mu;
    red[t] = d0 * d0 + d1 * d1 + d2 * d2 + d3 * d3;
    __syncthreads();
    for (int off = 128; off; off >>= 1) {
        if (t < off) red[t] += red[t + off];
        __syncthreads();
    }
    float rs = rsqrtf(red[0] * (1.f / 1024.f) + 1e-5f);
    int c = t * 4;
    ushort4 gv = *(const ushort4*)(g + c);
    ushort4 bv = *(const ushort4*)(b + c);
    ushort4 o;
    o.x = f2b(gelu_f(d0 * rs * b2f(gv.x) + b2f(bv.x)));
    o.y = f2b(gelu_f(d1 * rs * b2f(gv.y) + b2f(bv.y)));
    o.z = f2b(gelu_f(d2 * rs * b2f(gv.z) + b2f(bv.z)));
    o.w = f2b(gelu_f(d3 * rs * b2f(gv.w) + b2f(bv.w)));
    *(ushort4*)(out + (size_t)row * 1024 + c) = o;
}

// ---------------- final dot: out[i] = h[i,0:128] . w3 + b3  (f32 out) --------
__global__ __launch_bounds__(256) void k_final(const u16* __restrict__ h, const u16* __restrict__ w3,
                                               const u16* __restrict__ b3, float* __restrict__ out) {
    int gw = (blockIdx.x * 256 + threadIdx.x) >> 6;
    int lane = threadIdx.x & 63;
    if (gw >= NN) return;
    u32 hv = *(const u32*)(h + (size_t)gw * 128 + lane * 2);
    u32 wv = *(const u32*)(w3 + lane * 2);
    float s = b2f((u16)(hv & 0xffff)) * b2f((u16)(wv & 0xffff)) +
              b2f((u16)(hv >> 16)) * b2f((u16)(wv >> 16));
    for (int off = 32; off; off >>= 1) s += __shfl_down(s, off);
    if (lane == 0) out[gw] = s + b2f(b3[0]);
}

extern "C" void kernel_launch(void* const* d_in, const int* in_sizes, int n_in,
                              void* d_out, int out_size, void* d_ws, size_t ws_size,
                              hipStream_t stream) {
    (void)in_sizes; (void)n_in; (void)out_size; (void)ws_size;
    const float* x  = (const float*)d_in[0];
    const int*   ei = (const int*)d_in[1];
    float* out = (float*)d_out;

    char* p = (char*)d_ws;
    auto alloc = [&](size_t bytes) { char* q = p; p += (bytes + 255) & ~(size_t)255; return q; };
    int*   cnt    = (int*)alloc(NN * 4);
    int*   rowptr = (int*)alloc((NN + 1) * 4);
    int*   cursor = (int*)alloc(NN * 4);
    float* dinv   = (float*)alloc(NN * 4);
    int*   cols   = (int*)alloc(EE * 4);
    float* vals   = (float*)alloc(EE * 4);
    u16*   xp     = (u16*)alloc((size_t)MPAD * 96 * 2);
    u16*   wbuf   = (u16*)alloc((size_t)2678784 * 2);
    u16*   smallC = (u16*)alloc(10240 * 2);
    u16*   S1     = (u16*)alloc((size_t)MPAD * 256 * 2);
    u16*   S2     = (u16*)alloc((size_t)MPAD * 256 * 2);
    u16*   S3     = (u16*)alloc((size_t)MPAD * 256 * 2);
    u16*   S4     = (u16*)alloc((size_t)MPAD * 256 * 2);
    u16*   Zb     = (u16*)alloc((size_t)MPAD * 768 * 2);
    u16*   Y2     = (u16*)alloc((size_t)MPAD * 512 * 2);
    u16*   Y3     = (u16*)alloc((size_t)MPAD * 256 * 2);
    u16*   bufA   = (u16*)alloc((size_t)MPAD * 1024 * 2);
    float* concat = (float*)alloc((size_t)MPAD * 1024 * 4);
    // ~122 MB total (ws = 256 MiB per round-4 profile)

    u16* winT  = wbuf;             // [256][96]
    u16* w0T   = wbuf + 24576;     // [4][256][256]
    u16* w12T  = wbuf + 286720;    // [8][256][1024]
    u16* w1T   = wbuf + 2383872;   // [256][1024]
    u16* w2T   = wbuf + 2646016;   // [128][256]
    u16* binC  = smallC;
    u16* mb0C  = smallC + 256;
    u16* mb12C = smallC + 1280;
    u16* lngC  = smallC + 3328;
    u16* lnbC  = smallC + 6400;
    u16* b1C   = smallC + 9472;
    u16* b2C   = smallC + 9728;
    u16* w3C   = smallC + 9856;
    u16* b3C   = smallC + 9984;

    const int* srcA = ei;
    const int* dstA = ei + EE;

    hipMemsetAsync(cnt, 0, NN * 4, stream);

    k_padx<<<(MPAD * 96 + 255) / 256, 256, 0, stream>>>(x, xp);
    TransSrcs TS{(const float*)d_in[2], (const float*)d_in[4], (const float*)d_in[6],
                 (const float*)d_in[10], (const float*)d_in[12]};
    k_trans_all<<<(2678784 + 255) / 256, 256, 0, stream>>>(TS, wbuf);
    CvtSrcs CS{(const float*)d_in[3], (const float*)d_in[5], (const float*)d_in[7],
               (const float*)d_in[8], (const float*)d_in[9], (const float*)d_in[11],
               (const float*)d_in[13], (const float*)d_in[14], (const float*)d_in[15]};
    k_cvt_all<<<40, 256, 0, stream>>>(CS, smallC);

    k_count<<<(EE + 255) / 256, 256, 0, stream>>>(dstA, cnt);
    k_scan<<<1, 256, 0, stream>>>(cnt, rowptr, cursor, dinv);
    k_fill<<<(EE + 255) / 256, 256, 0, stream>>>(srcA, dstA, cursor, cols, vals, dinv);

    // input GEMM: S1 = gelu(xp @ winT^T + b_in)   [MPAD,256], K=96
    k_gemm128<1, 0, 0><<<dim3(79, 2), 256, 0, stream>>>(xp, xp, xp, xp, winT, binC, S1, nullptr, 96, 256, 0);

    // ---- layer 0: prop chain then batched GEMM ----
    k_propw<0><<<2500, 256, 0, stream>>>(S1, 256, 1, rowptr, cols, vals, dinv, nullptr, nullptr, 0, S2);
    k_propw<0><<<2500, 256, 0, stream>>>(S2, 256, 1, rowptr, cols, vals, dinv, nullptr, nullptr, 0, S3);
    k_propw<0><<<2500, 256, 0, stream>>>(S3, 256, 1, rowptr, cols, vals, dinv, nullptr, nullptr, 0, S4);
    k_gemm128<0, 1, 1><<<dim3(79, 2, 4), 256, 0, stream>>>(S1, S2, S3, S4, w0T, mb0C, concat, nullptr, 256, 1024, 0);
    k_ln_gelu<<<NN, 256, 0, stream>>>(concat, lngC, lnbC, bufA);

    // ---- layers 1,2: merged GEMM (N=1024) + shared prop chain ----
    for (int L = 0; L < 2; L++) {
        const u16* WT = w12T + (size_t)L * 1024 * 1024;
        const u16* BB = mb12C + L * 1024;
        // split epilogue: cols 0-255 -> concat f32 (+b0); cols 256-1023 -> Zb bf16
        k_gemm128<0, 2, 0><<<dim3(79, 8), 256, 0, stream>>>(bufA, bufA, bufA, bufA, WT, BB, concat, Zb, 1024, 0, 0);
        // Y1 = A*[z1 z2 z3]: g0 -> concat col 256 (+b1); rest -> Y2 [.,512]
        k_propw<1><<<7500, 256, 0, stream>>>(Zb, 768, 3, rowptr, cols, vals, dinv, concat, BB + 256, 256, Y2);
        // Y2: g0 -> concat col 512 (+b2); rest -> Y3 [.,256]
        k_propw<1><<<5000, 256, 0, stream>>>(Y2, 512, 2, rowptr, cols, vals, dinv, concat, BB + 512, 512, Y3);
        // Y3: -> concat col 768 (+b3)
        k_propw<1><<<2500, 256, 0, stream>>>(Y3, 256, 1, rowptr, cols, vals, dinv, concat, BB + 768, 768, Y3);
        k_ln_gelu<<<NN, 256, 0, stream>>>(concat, lngC + (L + 1) * 1024, lnbC + (L + 1) * 1024, bufA);
    }

    // ---- final MLP ----
    k_gemm128<1, 0, 0><<<dim3(79, 2), 256, 0, stream>>>(bufA, bufA, bufA, bufA, w1T, b1C, S1, nullptr, 1024, 256, 0);
    k_gemm128<1, 0, 0><<<dim3(79, 1), 256, 0, stream>>>(S1, S1, S1, S1, w2T, b2C, S2, nullptr, 256, 128, 0);
    k_final<<<2500, 256, 0, stream>>>(S2, w3C, b3C, out);
}

// Round 6
// 588.332 us; speedup vs baseline: 1.3054x; 1.0140x over previous
//
#include <hip/hip_runtime.h>

typedef unsigned short u16;
typedef unsigned int u32;
typedef __bf16 bf16x8 __attribute__((ext_vector_type(8)));
typedef float f32x4 __attribute__((ext_vector_type(4)));

#define NN 10000
#define EE 160000
#define MPAD 10112   // 79 * 128

__device__ inline float b2f(u16 u) { return __uint_as_float(((u32)u) << 16); }
__device__ inline u16 f2b(float f) {
    u32 u = __float_as_uint(f);
    return (u16)((u + 0x7fffu + ((u >> 16) & 1u)) >> 16);   // RNE
}
__device__ inline float gelu_f(float x) {
    return 0.5f * x * (1.0f + erff(x * 0.70710678118654752f));
}
__device__ inline void load_lds16(const u16* g, u16* l) {
    __builtin_amdgcn_global_load_lds((const __attribute__((address_space(1))) u32*)g,
                                     (__attribute__((address_space(3))) u32*)l, 16, 0, 0);
}

// ---------------- CSR build ----------------
__global__ __launch_bounds__(256) void k_count(const int* __restrict__ dst, int* __restrict__ cnt) {
    int e = blockIdx.x * 256 + threadIdx.x;
    if (e < EE) atomicAdd(&cnt[dst[e]], 1);
}

__global__ __launch_bounds__(256) void k_scan(const int* __restrict__ cnt, int* __restrict__ rowptr,
                                              int* __restrict__ cursor, float* __restrict__ dinv) {
    __shared__ int part[256];
    const int t = threadIdx.x;
    const int CH = 40;
    int base = t * CH;
    int ssum = 0;
    for (int k = 0; k < CH; k++) { int i = base + k; if (i < NN) ssum += cnt[i]; }
    part[t] = ssum;
    __syncthreads();
    for (int off = 1; off < 256; off <<= 1) {
        int v = (t >= off) ? part[t - off] : 0;
        __syncthreads();
        part[t] += v;
        __syncthreads();
    }
    int run = part[t] - ssum;
    for (int k = 0; k < CH; k++) {
        int i = base + k;
        if (i < NN) {
            rowptr[i] = run; cursor[i] = run;
            int c = cnt[i];
            dinv[i] = rsqrtf((float)(c + 1));
            run += c;
        }
    }
    if (t == 255) rowptr[NN] = run;
}

__global__ __launch_bounds__(256) void k_fill(const int* __restrict__ src, const int* __restrict__ dst,
                                              int* __restrict__ cursor, int* __restrict__ cols,
                                              float* __restrict__ vals, const float* __restrict__ dinv) {
    int e = blockIdx.x * 256 + threadIdx.x;
    if (e < EE) {
        int s = src[e], d = dst[e];
        int pos = atomicAdd(&cursor[d], 1);
        cols[pos] = s;
        vals[pos] = dinv[s] * dinv[d];
    }
}

// ---------------- ingest (f32 inputs -> bf16 ws copies) ----------------
__global__ __launch_bounds__(256) void k_padx(const float* __restrict__ x, u16* __restrict__ xp) {
    int idx = blockIdx.x * 256 + threadIdx.x;
    if (idx >= MPAD * 96) return;
    int r = idx / 96, c = idx - r * 96;
    u16 v = 0;
    if (r < NN && c < 84) v = f2b(x[(size_t)r * 84 + c]);
    xp[idx] = v;
}

struct TransSrcs { const float *w_in, *mh_w0, *mh_w12, *w1, *w2; };
__global__ __launch_bounds__(256) void k_trans_all(TransSrcs S, u16* __restrict__ wbuf) {
    int idx = blockIdx.x * 256 + threadIdx.x;
    const float* src; int local, Kp, K, Nc;
    if (idx < 24576)        { src = S.w_in;   local = idx;           Kp = 96;   K = 84;   Nc = 256; }
    else if (idx < 286720)  { src = S.mh_w0;  local = idx - 24576;   Kp = 256;  K = 256;  Nc = 256; }
    else if (idx < 2383872) { src = S.mh_w12; local = idx - 286720;  Kp = 1024; K = 1024; Nc = 256; }
    else if (idx < 2646016) { src = S.w1;     local = idx - 2383872; Kp = 1024; K = 1024; Nc = 256; }
    else if (idx < 2678784) { src = S.w2;     local = idx - 2646016; Kp = 256;  K = 256;  Nc = 128; }
    else return;
    int b   = local / (Nc * Kp);
    int rem = local - b * Nc * Kp;
    int nr  = rem / Kp;
    int k   = rem - nr * Kp;
    u16 v = 0;
    if (k < K) v = f2b(src[(size_t)b * K * Nc + (size_t)k * Nc + nr]);
    wbuf[idx] = v;
}

struct CvtSrcs { const float *b_in, *mh_b0, *mh_b12, *ln_g, *ln_b, *b1, *b2, *w3, *b3; };
__global__ __launch_bounds__(256) void k_cvt_all(CvtSrcs S, u16* __restrict__ dst) {
    int i = blockIdx.x * 256 + threadIdx.x;
    const float* s; int base;
    if (i < 256)       { s = S.b_in;   base = 0; }
    else if (i < 1280) { s = S.mh_b0;  base = 256; }
    else if (i < 3328) { s = S.mh_b12; base = 1280; }
    else if (i < 6400) { s = S.ln_g;   base = 3328; }
    else if (i < 9472) { s = S.ln_b;   base = 6400; }
    else if (i < 9728) { s = S.b1;     base = 9472; }
    else if (i < 9856) { s = S.b2;     base = 9728; }
    else if (i < 9984) { s = S.w3;     base = 9856; }
    else if (i < 9985) { s = S.b3;     base = 9984; }
    else return;
    dst[i] = f2b(s[i - base]);
}

// ---------------- 128x128 MFMA GEMM, global_load_lds staging ----------------
// XCD-swizzled 1D grid: id -> (g = id&7 [presumed XCD], s = id>>3), n = s%NB_N,
// j = s/NB_N, mb = g + 8*j. All NB_N column-tiles of one A-row-tile share g ->
// A-tile stays in that XCD's L2 (fetch ~1x instead of NB_N x).
// LDS XOR swizzle: col-block slot = cb ^ (row&3) -> 8-way conflicts drop to 4-way.
// EPI 0: bf16 C = [gelu](acc + bias) at [row][ldc]+col0.
// EPI 2: col<256 -> concat bf16 stride 1024 (+bias); col>=256 -> Z bf16 stride 768.
// BATCH: blockIdx.y selects A among A0..A3, offsets Bt/bias/col0 by z*256.
template<int ACT, int EPI, int BATCH>
__global__ __launch_bounds__(256) void k_gemm128(const u16* __restrict__ A0, const u16* __restrict__ A1,
                                                 const u16* __restrict__ A2, const u16* __restrict__ A3,
                                                 const u16* __restrict__ Bt, const u16* __restrict__ bias,
                                                 u16* __restrict__ C, u16* __restrict__ Z,
                                                 int K, int ldc, int col0, int NB_M, int NB_N) {
    __shared__ __align__(16) u16 As[128 * 32];
    __shared__ __align__(16) u16 Bs[128 * 32];
    int id = blockIdx.x;
    int g8 = id & 7, sIdx = id >> 3;
    int nb = sIdx % NB_N, jb = sIdx / NB_N;
    int mb = g8 + 8 * jb;
    if (mb >= NB_M) return;
    const u16* A = A0;
    if (BATCH) {
        int z = blockIdx.y;
        if (z == 1) A = A1; else if (z == 2) A = A2; else if (z == 3) A = A3;
        Bt   += (size_t)z * 256 * K;
        bias += z * 256;
        col0 += z * 256;
    }
    const int t = threadIdx.x;
    const int wv = t >> 6, lane = t & 63;
    const int wm = wv >> 1, wn = wv & 1;
    const int quad = lane >> 4, l16 = lane & 15;
    const int tileM = mb * 128, tileN = nb * 128;

    f32x4 acc[4][4] = {};

    const int rch = lane >> 2;                         // row within 16-row chunk
    const int c8s = ((lane & 3) ^ (rch & 3)) * 8;      // XOR-swizzled col-block
    const int ch0 = wv * 2, ch1 = wv * 2 + 1;
    const u16* ga0 = A  + (size_t)(tileM + ch0 * 16 + rch) * K + c8s;
    const u16* ga1 = A  + (size_t)(tileM + ch1 * 16 + rch) * K + c8s;
    const u16* gb0 = Bt + (size_t)(tileN + ch0 * 16 + rch) * K + c8s;
    const u16* gb1 = Bt + (size_t)(tileN + ch1 * 16 + rch) * K + c8s;
    u16* la0 = &As[ch0 * 512 + lane * 8];
    u16* la1 = &As[ch1 * 512 + lane * 8];
    u16* lb0 = &Bs[ch0 * 512 + lane * 8];
    u16* lb1 = &Bs[ch1 * 512 + lane * 8];

    for (int k0 = 0; k0 < K; k0 += 32) {
        __syncthreads();
        load_lds16(ga0 + k0, la0);
        load_lds16(ga1 + k0, la1);
        load_lds16(gb0 + k0, lb0);
        load_lds16(gb1 + k0, lb1);
        __syncthreads();
        bf16x8 af[4], bfr[4];
#pragma unroll
        for (int tm = 0; tm < 4; tm++) {
            int R = wm * 64 + tm * 16 + l16;
            af[tm] = *(const bf16x8*)&As[R * 32 + ((quad ^ (l16 & 3)) * 8)];
        }
#pragma unroll
        for (int tn = 0; tn < 4; tn++) {
            int R = wn * 64 + tn * 16 + l16;
            bfr[tn] = *(const bf16x8*)&Bs[R * 32 + ((quad ^ (l16 & 3)) * 8)];
        }
#pragma unroll
        for (int tm = 0; tm < 4; tm++)
#pragma unroll
            for (int tn = 0; tn < 4; tn++)
                acc[tm][tn] = __builtin_amdgcn_mfma_f32_16x16x32_bf16(af[tm], bfr[tn], acc[tm][tn], 0, 0, 0);
    }

#pragma unroll
    for (int tm = 0; tm < 4; tm++)
#pragma unroll
        for (int tn = 0; tn < 4; tn++)
#pragma unroll
            for (int r = 0; r < 4; r++) {
                int row = tileM + wm * 64 + tm * 16 + quad * 4 + r;
                int col = tileN + wn * 64 + tn * 16 + l16;
                float v = acc[tm][tn][r];
                if (EPI == 2) {
                    if (col < 256) C[(size_t)row * 1024 + col] = f2b(v + b2f(bias[col]));
                    else           Z[(size_t)row * 768 + (col - 256)] = f2b(v);
                } else {
                    v += b2f(bias[col]);
                    if (ACT) v = gelu_f(v);
                    C[(size_t)row * ldc + col0 + col] = f2b(v);
                }
            }
}

// ---------------- wide propagation ----------------
// hin: [.., W] bf16 (W = 256*G). One wave per (node, 256-col group).
// group 0 (if CAT0): -> concat bf16 [node][1024] at col0, + bias.
// other groups:      -> out2 bf16, stride W - 256*CAT0.
template<int CAT0>
__global__ __launch_bounds__(256) void k_propw(const u16* __restrict__ hin, int W, int G,
                                               const int* __restrict__ rowptr, const int* __restrict__ cols,
                                               const float* __restrict__ vals, const float* __restrict__ dinv,
                                               u16* __restrict__ concat, const u16* __restrict__ bias,
                                               int col0, u16* __restrict__ out2) {
    int unit = blockIdx.x * 4 + (threadIdx.x >> 6);
    if (unit >= NN * G) return;
    int node = unit / G, g = unit - node * G;
    int lane = threadIdx.x & 63;
    int half = lane >> 5, fl = lane & 31;
    const u16* base = hin + g * 256 + fl * 8;
    float a0 = 0, a1 = 0, a2 = 0, a3 = 0, a4 = 0, a5 = 0, a6 = 0, a7 = 0;
    int s = rowptr[node], e = rowptr[node + 1];
    for (int q = s + half; q < e; q += 2) {
        int j = cols[q];
        float w = vals[q];
        bf16x8 v = *(const bf16x8*)(base + (size_t)j * W);
        a0 += w * (float)v[0]; a1 += w * (float)v[1]; a2 += w * (float)v[2]; a3 += w * (float)v[3];
        a4 += w * (float)v[4]; a5 += w * (float)v[5]; a6 += w * (float)v[6]; a7 += w * (float)v[7];
    }
    a0 += __shfl_down(a0, 32); a1 += __shfl_down(a1, 32);
    a2 += __shfl_down(a2, 32); a3 += __shfl_down(a3, 32);
    a4 += __shfl_down(a4, 32); a5 += __shfl_down(a5, 32);
    a6 += __shfl_down(a6, 32); a7 += __shfl_down(a7, 32);
    if (half == 0) {
        float di = dinv[node], sw = di * di;
        bf16x8 sv = *(const bf16x8*)(base + (size_t)node * W);
        a0 += sw * (float)sv[0]; a1 += sw * (float)sv[1]; a2 += sw * (float)sv[2]; a3 += sw * (float)sv[3];
        a4 += sw * (float)sv[4]; a5 += sw * (float)sv[5]; a6 += sw * (float)sv[6]; a7 += sw * (float)sv[7];
        int f = fl * 8;
        union { u16 u[8]; uint4 v; } pk;
        if (CAT0 && g == 0) {
            pk.u[0] = f2b(a0 + b2f(bias[f + 0])); pk.u[1] = f2b(a1 + b2f(bias[f + 1]));
            pk.u[2] = f2b(a2 + b2f(bias[f + 2])); pk.u[3] = f2b(a3 + b2f(bias[f + 3]));
            pk.u[4] = f2b(a4 + b2f(bias[f + 4])); pk.u[5] = f2b(a5 + b2f(bias[f + 5]));
            pk.u[6] = f2b(a6 + b2f(bias[f + 6])); pk.u[7] = f2b(a7 + b2f(bias[f + 7]));
            *(uint4*)(concat + (size_t)node * 1024 + col0 + f) = pk.v;
        } else {
            int W2 = W - CAT0 * 256;
            pk.u[0] = f2b(a0); pk.u[1] = f2b(a1); pk.u[2] = f2b(a2); pk.u[3] = f2b(a3);
            pk.u[4] = f2b(a4); pk.u[5] = f2b(a5); pk.u[6] = f2b(a6); pk.u[7] = f2b(a7);
            *(uint4*)(out2 + (size_t)node * W2 + (g - CAT0) * 256 + f) = pk.v;
        }
    }
}

// ---------------- LayerNorm(1024) + gelu, bf16 in -> bf16 out ----------------
__global__ __launch_bounds__(256) void k_ln_gelu(const u16* __restrict__ X, const u16* __restrict__ g,
                                                 const u16* __restrict__ b, u16* __restrict__ out) {
    __shared__ float red[256];
    const int row = blockIdx.x, t = threadIdx.x;
    ushort4 xv = *(const ushort4*)(X + (size_t)row * 1024 + t * 4);
    float x0 = b2f(xv.x), x1 = b2f(xv.y), x2 = b2f(xv.z), x3 = b2f(xv.w);
    red[t] = x0 + x1 + x2 + x3;
    __syncthreads();
    for (int off = 128; off; off >>= 1) {
        if (t < off) red[t] += red[t + off];
        __syncthreads();
    }
    float mu = red[0] * (1.f / 1024.f);
    __syncthreads();
    float d0 = x0 - mu, d1 = x1 - mu, d2 = x2 - mu, d3 = x3 - mu;
    red[t] = d0 * d0 + d1 * d1 + d2 * d2 + d3 * d3;
    __syncthreads();
    for (int off = 128; off; off >>= 1) {
        if (t < off) red[t] += red[t + off];
        __syncthreads();
    }
    float rs = rsqrtf(red[0] * (1.f / 1024.f) + 1e-5f);
    int c = t * 4;
    ushort4 gv = *(const ushort4*)(g + c);
    ushort4 bv = *(const ushort4*)(b + c);
    ushort4 o;
    o.x = f2b(gelu_f(d0 * rs * b2f(gv.x) + b2f(bv.x)));
    o.y = f2b(gelu_f(d1 * rs * b2f(gv.y) + b2f(bv.y)));
    o.z = f2b(gelu_f(d2 * rs * b2f(gv.z) + b2f(bv.z)));
    o.w = f2b(gelu_f(d3 * rs * b2f(gv.w) + b2f(bv.w)));
    *(ushort4*)(out + (size_t)row * 1024 + c) = o;
}

// ---------------- final dot: out[i] = h[i,0:128] . w3 + b3  (f32 out) --------
__global__ __launch_bounds__(256) void k_final(const u16* __restrict__ h, const u16* __restrict__ w3,
                                               const u16* __restrict__ b3, float* __restrict__ out) {
    int gw = (blockIdx.x * 256 + threadIdx.x) >> 6;
    int lane = threadIdx.x & 63;
    if (gw >= NN) return;
    u32 hv = *(const u32*)(h + (size_t)gw * 128 + lane * 2);
    u32 wv = *(const u32*)(w3 + lane * 2);
    float s = b2f((u16)(hv & 0xffff)) * b2f((u16)(wv & 0xffff)) +
              b2f((u16)(hv >> 16)) * b2f((u16)(wv >> 16));
    for (int off = 32; off; off >>= 1) s += __shfl_down(s, off);
    if (lane == 0) out[gw] = s + b2f(b3[0]);
}

extern "C" void kernel_launch(void* const* d_in, const int* in_sizes, int n_in,
                              void* d_out, int out_size, void* d_ws, size_t ws_size,
                              hipStream_t stream) {
    (void)in_sizes; (void)n_in; (void)out_size; (void)ws_size;
    const float* x  = (const float*)d_in[0];
    const int*   ei = (const int*)d_in[1];
    float* out = (float*)d_out;

    char* p = (char*)d_ws;
    auto alloc = [&](size_t bytes) { char* q = p; p += (bytes + 255) & ~(size_t)255; return q; };
    int*   cnt    = (int*)alloc(NN * 4);
    int*   rowptr = (int*)alloc((NN + 1) * 4);
    int*   cursor = (int*)alloc(NN * 4);
    float* dinv   = (float*)alloc(NN * 4);
    int*   cols   = (int*)alloc(EE * 4);
    float* vals   = (float*)alloc(EE * 4);
    u16*   xp     = (u16*)alloc((size_t)MPAD * 96 * 2);
    u16*   wbuf   = (u16*)alloc((size_t)2678784 * 2);
    u16*   smallC = (u16*)alloc(10240 * 2);
    u16*   S1     = (u16*)alloc((size_t)MPAD * 256 * 2);
    u16*   S2     = (u16*)alloc((size_t)MPAD * 256 * 2);
    u16*   S3     = (u16*)alloc((size_t)MPAD * 256 * 2);
    u16*   S4     = (u16*)alloc((size_t)MPAD * 256 * 2);
    u16*   Zb     = (u16*)alloc((size_t)MPAD * 768 * 2);
    u16*   Y2     = (u16*)alloc((size_t)MPAD * 512 * 2);
    u16*   Y3     = (u16*)alloc((size_t)MPAD * 256 * 2);
    u16*   bufA   = (u16*)alloc((size_t)MPAD * 1024 * 2);
    u16*   concat = (u16*)alloc((size_t)MPAD * 1024 * 2);

    u16* winT  = wbuf;             // [256][96]
    u16* w0T   = wbuf + 24576;     // [4][256][256]
    u16* w12T  = wbuf + 286720;    // [8][256][1024]
    u16* w1T   = wbuf + 2383872;   // [256][1024]
    u16* w2T   = wbuf + 2646016;   // [128][256]
    u16* binC  = smallC;
    u16* mb0C  = smallC + 256;
    u16* mb12C = smallC + 1280;
    u16* lngC  = smallC + 3328;
    u16* lnbC  = smallC + 6400;
    u16* b1C   = smallC + 9472;
    u16* b2C   = smallC + 9728;
    u16* w3C   = smallC + 9856;
    u16* b3C   = smallC + 9984;

    const int* srcA = ei;
    const int* dstA = ei + EE;

    hipMemsetAsync(cnt, 0, NN * 4, stream);

    k_padx<<<(MPAD * 96 + 255) / 256, 256, 0, stream>>>(x, xp);
    TransSrcs TS{(const float*)d_in[2], (const float*)d_in[4], (const float*)d_in[6],
                 (const float*)d_in[10], (const float*)d_in[12]};
    k_trans_all<<<(2678784 + 255) / 256, 256, 0, stream>>>(TS, wbuf);
    CvtSrcs CS{(const float*)d_in[3], (const float*)d_in[5], (const float*)d_in[7],
               (const float*)d_in[8], (const float*)d_in[9], (const float*)d_in[11],
               (const float*)d_in[13], (const float*)d_in[14], (const float*)d_in[15]};
    k_cvt_all<<<40, 256, 0, stream>>>(CS, smallC);

    k_count<<<(EE + 255) / 256, 256, 0, stream>>>(dstA, cnt);
    k_scan<<<1, 256, 0, stream>>>(cnt, rowptr, cursor, dinv);
    k_fill<<<(EE + 255) / 256, 256, 0, stream>>>(srcA, dstA, cursor, cols, vals, dinv);

    // swizzled grid sizes: 8 * ceil(79/8) * NB_N
    const int G1 = 80 * 1, G2 = 80 * 2, G8 = 80 * 8;

    // input GEMM: S1 = gelu(xp @ winT^T + b_in)   [MPAD,256], K=96
    k_gemm128<1, 0, 0><<<G2, 256, 0, stream>>>(xp, xp, xp, xp, winT, binC, S1, nullptr, 96, 256, 0, 79, 2);

    // ---- layer 0: prop chain then batched GEMM (writes concat bf16) ----
    k_propw<0><<<2500, 256, 0, stream>>>(S1, 256, 1, rowptr, cols, vals, dinv, nullptr, nullptr, 0, S2);
    k_propw<0><<<2500, 256, 0, stream>>>(S2, 256, 1, rowptr, cols, vals, dinv, nullptr, nullptr, 0, S3);
    k_propw<0><<<2500, 256, 0, stream>>>(S3, 256, 1, rowptr, cols, vals, dinv, nullptr, nullptr, 0, S4);
    k_gemm128<0, 0, 1><<<dim3(G2, 4), 256, 0, stream>>>(S1, S2, S3, S4, w0T, mb0C, concat, nullptr, 256, 1024, 0, 79, 2);
    k_ln_gelu<<<NN, 256, 0, stream>>>(concat, lngC, lnbC, bufA);

    // ---- layers 1,2: merged GEMM (N=1024) + shared prop chain ----
    for (int L = 0; L < 2; L++) {
        const u16* WT = w12T + (size_t)L * 1024 * 1024;
        const u16* BB = mb12C + L * 1024;
        // split epilogue: cols 0-255 -> concat (+b0); cols 256-1023 -> Zb
        k_gemm128<0, 2, 0><<<G8, 256, 0, stream>>>(bufA, bufA, bufA, bufA, WT, BB, concat, Zb, 1024, 0, 0, 79, 8);
        // Y1 = A*[z1 z2 z3]: g0 -> concat col 256 (+b1); rest -> Y2 [.,512]
        k_propw<1><<<7500, 256, 0, stream>>>(Zb, 768, 3, rowptr, cols, vals, dinv, concat, BB + 256, 256, Y2);
        // Y2: g0 -> concat col 512 (+b2); rest -> Y3 [.,256]
        k_propw<1><<<5000, 256, 0, stream>>>(Y2, 512, 2, rowptr, cols, vals, dinv, concat, BB + 512, 512, Y3);
        // Y3: -> concat col 768 (+b3)
        k_propw<1><<<2500, 256, 0, stream>>>(Y3, 256, 1, rowptr, cols, vals, dinv, concat, BB + 768, 768, Y3);
        k_ln_gelu<<<NN, 256, 0, stream>>>(concat, lngC + (L + 1) * 1024, lnbC + (L + 1) * 1024, bufA);
    }

    // ---- final MLP ----
    k_gemm128<1, 0, 0><<<G2, 256, 0, stream>>>(bufA, bufA, bufA, bufA, w1T, b1C, S1, nullptr, 1024, 256, 0, 79, 2);
    k_gemm128<1, 0, 0><<<G1, 256, 0, stream>>>(S1, S1, S1, S1, w2T, b2C, S2, nullptr, 256, 128, 0, 79, 1);
    k_final<<<2500, 256, 0, stream>>>(S2, w3C, b3C, out);
}

// Round 7
// 519.767 us; speedup vs baseline: 1.4777x; 1.1319x over previous
//
#include <hip/hip_runtime.h>

typedef unsigned short u16;
typedef unsigned int u32;
typedef __bf16 bf16x8 __attribute__((ext_vector_type(8)));
typedef float f32x4 __attribute__((ext_vector_type(4)));

#define NN 10000
#define EE 160000
#define MPAD 10112   // 79 * 128 = 158 * 64

__device__ inline float b2f(u16 u) { return __uint_as_float(((u32)u) << 16); }
__device__ inline u16 f2b(float f) {
    u32 u = __float_as_uint(f);
    return (u16)((u + 0x7fffu + ((u >> 16) & 1u)) >> 16);   // RNE
}
__device__ inline float gelu_f(float x) {
    return 0.5f * x * (1.0f + erff(x * 0.70710678118654752f));
}
__device__ inline void load_lds16(const u16* g, u16* l) {
    __builtin_amdgcn_global_load_lds((const __attribute__((address_space(1))) u32*)g,
                                     (__attribute__((address_space(3))) u32*)l, 16, 0, 0);
}

// ---------------- CSR build ----------------
__global__ __launch_bounds__(256) void k_count(const int* __restrict__ dst, int* __restrict__ cnt) {
    int e = blockIdx.x * 256 + threadIdx.x;
    if (e < EE) atomicAdd(&cnt[dst[e]], 1);
}

__global__ __launch_bounds__(256) void k_scan(const int* __restrict__ cnt, int* __restrict__ rowptr,
                                              int* __restrict__ cursor, float* __restrict__ dinv) {
    __shared__ int part[256];
    const int t = threadIdx.x;
    const int CH = 40;
    int base = t * CH;
    int ssum = 0;
    for (int k = 0; k < CH; k++) { int i = base + k; if (i < NN) ssum += cnt[i]; }
    part[t] = ssum;
    __syncthreads();
    for (int off = 1; off < 256; off <<= 1) {
        int v = (t >= off) ? part[t - off] : 0;
        __syncthreads();
        part[t] += v;
        __syncthreads();
    }
    int run = part[t] - ssum;
    for (int k = 0; k < CH; k++) {
        int i = base + k;
        if (i < NN) {
            rowptr[i] = run; cursor[i] = run;
            int c = cnt[i];
            dinv[i] = rsqrtf((float)(c + 1));
            run += c;
        }
    }
    if (t == 255) rowptr[NN] = run;
}

__global__ __launch_bounds__(256) void k_fill(const int* __restrict__ src, const int* __restrict__ dst,
                                              int* __restrict__ cursor, int* __restrict__ cols,
                                              float* __restrict__ vals, const float* __restrict__ dinv) {
    int e = blockIdx.x * 256 + threadIdx.x;
    if (e < EE) {
        int s = src[e], d = dst[e];
        int pos = atomicAdd(&cursor[d], 1);
        cols[pos] = s;
        vals[pos] = dinv[s] * dinv[d];
    }
}

// ---------------- ingest ----------------
__global__ __launch_bounds__(256) void k_padx(const float* __restrict__ x, u16* __restrict__ xp) {
    int idx = blockIdx.x * 256 + threadIdx.x;
    if (idx >= MPAD * 96) return;
    int r = idx / 96, c = idx - r * 96;
    u16 v = 0;
    if (r < NN && c < 84) v = f2b(x[(size_t)r * 84 + c]);
    xp[idx] = v;
}

// LDS-tiled transpose: src [B][K][Nc] f32 -> dst [B][Nc][Kp] bf16 (zero-pad k>=K)
struct TT { const float* src; u16* dst; int K, Nc, Kp; };
__global__ __launch_bounds__(256) void k_transT(TT t0, TT t1, TT t2, TT t3, TT t4) {
    int b = blockIdx.x; TT T;
    if (b < 8)        { T = t0; }
    else if (b < 72)  { T = t1; b -= 8; }
    else if (b < 584) { T = t2; b -= 72; }
    else if (b < 648) { T = t3; b -= 584; }
    else              { T = t4; b -= 648; }
    int tk = (T.K + 63) >> 6, tn = T.Nc >> 6;
    int bb  = b / (tk * tn);
    int rem = b - bb * (tk * tn);
    int k0 = (rem / tn) * 64, n0 = (rem % tn) * 64;
    __shared__ u16 tile[64][65];
    const float* src = T.src + (size_t)bb * T.K * T.Nc;
    u16* dst = T.dst + (size_t)bb * T.Nc * T.Kp;
    int c = threadIdx.x & 63, r0 = threadIdx.x >> 6;
#pragma unroll
    for (int i = 0; i < 16; i++) {
        int r = r0 + i * 4;
        int k = k0 + r;
        u16 v = 0;
        if (k < T.K) v = f2b(src[(size_t)k * T.Nc + n0 + c]);
        tile[r][c] = v;
    }
    __syncthreads();
    int rr = threadIdx.x & 63, cc0 = threadIdx.x >> 6;
#pragma unroll
    for (int i = 0; i < 16; i++) {
        int cc = cc0 + i * 4;
        int k = k0 + rr;
        if (k < T.Kp) dst[(size_t)(n0 + cc) * T.Kp + k] = tile[rr][cc];
    }
}

struct CvtSrcs { const float *b_in, *mh_b0, *mh_b12, *ln_g, *ln_b, *b1, *b2, *w3, *b3; };
__global__ __launch_bounds__(256) void k_cvt_all(CvtSrcs S, u16* __restrict__ dst) {
    int i = blockIdx.x * 256 + threadIdx.x;
    const float* s; int base;
    if (i < 256)       { s = S.b_in;   base = 0; }
    else if (i < 1280) { s = S.mh_b0;  base = 256; }
    else if (i < 3328) { s = S.mh_b12; base = 1280; }
    else if (i < 6400) { s = S.ln_g;   base = 3328; }
    else if (i < 9472) { s = S.ln_b;   base = 6400; }
    else if (i < 9728) { s = S.b1;     base = 9472; }
    else if (i < 9856) { s = S.b2;     base = 9728; }
    else if (i < 9984) { s = S.w3;     base = 9856; }
    else if (i < 9985) { s = S.b3;     base = 9984; }
    else return;
    dst[i] = f2b(s[i - base]);
}

// ---------------- templated MFMA GEMM (TM x TN tile, 4 waves 2x2) ----------------
// XCD-swizzled 1D grid: id -> g8=id&7, sIdx=id>>3; nb=sIdx%NB_N, jb=sIdx/NB_N,
// mb=g8+8*jb. N-tiles of one A-row-tile share g8 -> A stays in that XCD's L2.
// EPI 0: bf16 C = [gelu](acc+bias) at [row][ldc]+col0.
// EPI 2: col<256 -> concat bf16 stride 1024 (+bias); col>=256 -> Z bf16 stride 768.
// BATCH: blockIdx.y selects A among A0..A3, offsets Bt/bias/col0 by z*256.
template<int TM, int TN, int ACT, int EPI, int BATCH>
__global__ __launch_bounds__(256) void k_gemm(const u16* __restrict__ A0, const u16* __restrict__ A1,
                                              const u16* __restrict__ A2, const u16* __restrict__ A3,
                                              const u16* __restrict__ Bt, const u16* __restrict__ bias,
                                              u16* __restrict__ C, u16* __restrict__ Z,
                                              int K, int ldc, int col0, int NB_M, int NB_N) {
    constexpr int AM = TM / 32, AN = TN / 32;       // per-wave 16x16 tiles
    constexpr int CA = TM / 16, CB = TN / 16;       // 16-row staging chunks
    constexpr int NCH = (CA + CB) / 4;              // chunks per wave
    __shared__ __align__(16) u16 As[TM * 32];
    __shared__ __align__(16) u16 Bs[TN * 32];
    int id = blockIdx.x;
    int g8 = id & 7, sIdx = id >> 3;
    int nb = sIdx % NB_N, jb = sIdx / NB_N;
    int mb = g8 + 8 * jb;
    if (mb >= NB_M) return;
    const u16* A = A0;
    if (BATCH) {
        int z = blockIdx.y;
        if (z == 1) A = A1; else if (z == 2) A = A2; else if (z == 3) A = A3;
        Bt   += (size_t)z * 256 * K;
        bias += z * 256;
        col0 += z * 256;
    }
    const int t = threadIdx.x;
    const int wv = t >> 6, lane = t & 63;
    const int wm = wv >> 1, wn = wv & 1;
    const int quad = lane >> 4, l16 = lane & 15;
    const int tileM = mb * TM, tileN = nb * TN;

    f32x4 acc[AM][AN] = {};

    const int rch = lane >> 2, c8 = (lane & 3) * 8;
    const u16* gsrc[NCH];
    u16* ldst[NCH];
#pragma unroll
    for (int i = 0; i < NCH; i++) {
        int c = wv + 4 * i;
        if (c < CA) {
            gsrc[i] = A + (size_t)(tileM + c * 16 + rch) * K + c8;
            ldst[i] = &As[c * 512 + lane * 8];
        } else {
            int cc = c - CA;
            gsrc[i] = Bt + (size_t)(tileN + cc * 16 + rch) * K + c8;
            ldst[i] = &Bs[cc * 512 + lane * 8];
        }
    }

    for (int k0 = 0; k0 < K; k0 += 32) {
        __syncthreads();
#pragma unroll
        for (int i = 0; i < NCH; i++) load_lds16(gsrc[i] + k0, ldst[i]);
        __syncthreads();
        bf16x8 af[AM], bfr[AN];
#pragma unroll
        for (int tm = 0; tm < AM; tm++)
            af[tm] = *(const bf16x8*)&As[(wm * (TM / 2) + tm * 16 + l16) * 32 + quad * 8];
#pragma unroll
        for (int tn = 0; tn < AN; tn++)
            bfr[tn] = *(const bf16x8*)&Bs[(wn * (TN / 2) + tn * 16 + l16) * 32 + quad * 8];
#pragma unroll
        for (int tm = 0; tm < AM; tm++)
#pragma unroll
            for (int tn = 0; tn < AN; tn++)
                acc[tm][tn] = __builtin_amdgcn_mfma_f32_16x16x32_bf16(af[tm], bfr[tn], acc[tm][tn], 0, 0, 0);
    }

#pragma unroll
    for (int tm = 0; tm < AM; tm++)
#pragma unroll
        for (int tn = 0; tn < AN; tn++)
#pragma unroll
            for (int r = 0; r < 4; r++) {
                int row = tileM + wm * (TM / 2) + tm * 16 + quad * 4 + r;
                int col = tileN + wn * (TN / 2) + tn * 16 + l16;
                float v = acc[tm][tn][r];
                if (EPI == 2) {
                    if (col < 256) C[(size_t)row * 1024 + col] = f2b(v + b2f(bias[col]));
                    else           Z[(size_t)row * 768 + (col - 256)] = f2b(v);
                } else {
                    v += b2f(bias[col]);
                    if (ACT) v = gelu_f(v);
                    C[(size_t)row * ldc + col0 + col] = f2b(v);
                }
            }
}

// ---------------- wide propagation (2x unrolled gather) ----------------
// hin: [.., W] bf16 (W = 256*G). One wave per (node, 256-col group).
// group 0 (if CAT0): -> concat bf16 [node][1024] at col0, + bias.
// other groups:      -> out2 bf16, stride W - 256*CAT0.
template<int CAT0>
__global__ __launch_bounds__(256) void k_propw(const u16* __restrict__ hin, int W, int G,
                                               const int* __restrict__ rowptr, const int* __restrict__ cols,
                                               const float* __restrict__ vals, const float* __restrict__ dinv,
                                               u16* __restrict__ concat, const u16* __restrict__ bias,
                                               int col0, u16* __restrict__ out2) {
    int unit = blockIdx.x * 4 + (threadIdx.x >> 6);
    if (unit >= NN * G) return;
    int node = unit / G, g = unit - node * G;
    int lane = threadIdx.x & 63;
    int half = lane >> 5, fl = lane & 31;
    const u16* base = hin + g * 256 + fl * 8;
    float a0 = 0, a1 = 0, a2 = 0, a3 = 0, a4 = 0, a5 = 0, a6 = 0, a7 = 0;
    if (half == 1) {   // self-loop handled by the upper half (balances work)
        float di = dinv[node], sw = di * di;
        bf16x8 sv = *(const bf16x8*)(base + (size_t)node * W);
        a0 = sw * (float)sv[0]; a1 = sw * (float)sv[1]; a2 = sw * (float)sv[2]; a3 = sw * (float)sv[3];
        a4 = sw * (float)sv[4]; a5 = sw * (float)sv[5]; a6 = sw * (float)sv[6]; a7 = sw * (float)sv[7];
    }
    int s = rowptr[node], e = rowptr[node + 1];
    int q = s + half;
    for (; q + 2 < e; q += 4) {     // two edges in flight per half-wave
        int j0 = cols[q],  j1 = cols[q + 2];
        float w0 = vals[q], w1 = vals[q + 2];
        bf16x8 v0 = *(const bf16x8*)(base + (size_t)j0 * W);
        bf16x8 v1 = *(const bf16x8*)(base + (size_t)j1 * W);
        a0 += w0 * (float)v0[0] + w1 * (float)v1[0];
        a1 += w0 * (float)v0[1] + w1 * (float)v1[1];
        a2 += w0 * (float)v0[2] + w1 * (float)v1[2];
        a3 += w0 * (float)v0[3] + w1 * (float)v1[3];
        a4 += w0 * (float)v0[4] + w1 * (float)v1[4];
        a5 += w0 * (float)v0[5] + w1 * (float)v1[5];
        a6 += w0 * (float)v0[6] + w1 * (float)v1[6];
        a7 += w0 * (float)v0[7] + w1 * (float)v1[7];
    }
    if (q < e) {
        int j = cols[q];
        float w = vals[q];
        bf16x8 v = *(const bf16x8*)(base + (size_t)j * W);
        a0 += w * (float)v[0]; a1 += w * (float)v[1]; a2 += w * (float)v[2]; a3 += w * (float)v[3];
        a4 += w * (float)v[4]; a5 += w * (float)v[5]; a6 += w * (float)v[6]; a7 += w * (float)v[7];
    }
    a0 += __shfl_down(a0, 32); a1 += __shfl_down(a1, 32);
    a2 += __shfl_down(a2, 32); a3 += __shfl_down(a3, 32);
    a4 += __shfl_down(a4, 32); a5 += __shfl_down(a5, 32);
    a6 += __shfl_down(a6, 32); a7 += __shfl_down(a7, 32);
    if (half == 0) {
        int f = fl * 8;
        union { u16 u[8]; uint4 v; } pk;
        if (CAT0 && g == 0) {
            pk.u[0] = f2b(a0 + b2f(bias[f + 0])); pk.u[1] = f2b(a1 + b2f(bias[f + 1]));
            pk.u[2] = f2b(a2 + b2f(bias[f + 2])); pk.u[3] = f2b(a3 + b2f(bias[f + 3]));
            pk.u[4] = f2b(a4 + b2f(bias[f + 4])); pk.u[5] = f2b(a5 + b2f(bias[f + 5]));
            pk.u[6] = f2b(a6 + b2f(bias[f + 6])); pk.u[7] = f2b(a7 + b2f(bias[f + 7]));
            *(uint4*)(concat + (size_t)node * 1024 + col0 + f) = pk.v;
        } else {
            int W2 = W - CAT0 * 256;
            pk.u[0] = f2b(a0); pk.u[1] = f2b(a1); pk.u[2] = f2b(a2); pk.u[3] = f2b(a3);
            pk.u[4] = f2b(a4); pk.u[5] = f2b(a5); pk.u[6] = f2b(a6); pk.u[7] = f2b(a7);
            *(uint4*)(out2 + (size_t)node * W2 + (g - CAT0) * 256 + f) = pk.v;
        }
    }
}

// ---------------- LayerNorm(1024) + gelu, bf16 in -> bf16 out ----------------
__global__ __launch_bounds__(256) void k_ln_gelu(const u16* __restrict__ X, const u16* __restrict__ g,
                                                 const u16* __restrict__ b, u16* __restrict__ out) {
    __shared__ float red[256];
    const int row = blockIdx.x, t = threadIdx.x;
    ushort4 xv = *(const ushort4*)(X + (size_t)row * 1024 + t * 4);
    float x0 = b2f(xv.x), x1 = b2f(xv.y), x2 = b2f(xv.z), x3 = b2f(xv.w);
    red[t] = x0 + x1 + x2 + x3;
    __syncthreads();
    for (int off = 128; off; off >>= 1) {
        if (t < off) red[t] += red[t + off];
        __syncthreads();
    }
    float mu = red[0] * (1.f / 1024.f);
    __syncthreads();
    float d0 = x0 - mu, d1 = x1 - mu, d2 = x2 - mu, d3 = x3 - mu;
    red[t] = d0 * d0 + d1 * d1 + d2 * d2 + d3 * d3;
    __syncthreads();
    for (int off = 128; off; off >>= 1) {
        if (t < off) red[t] += red[t + off];
        __syncthreads();
    }
    float rs = rsqrtf(red[0] * (1.f / 1024.f) + 1e-5f);
    int c = t * 4;
    ushort4 gv = *(const ushort4*)(g + c);
    ushort4 bv = *(const ushort4*)(b + c);
    ushort4 o;
    o.x = f2b(gelu_f(d0 * rs * b2f(gv.x) + b2f(bv.x)));
    o.y = f2b(gelu_f(d1 * rs * b2f(gv.y) + b2f(bv.y)));
    o.z = f2b(gelu_f(d2 * rs * b2f(gv.z) + b2f(bv.z)));
    o.w = f2b(gelu_f(d3 * rs * b2f(gv.w) + b2f(bv.w)));
    *(ushort4*)(out + (size_t)row * 1024 + c) = o;
}

// ---------------- final dot: out[i] = h[i,0:128] . w3 + b3  (f32 out) --------
__global__ __launch_bounds__(256) void k_final(const u16* __restrict__ h, const u16* __restrict__ w3,
                                               const u16* __restrict__ b3, float* __restrict__ out) {
    int gw = (blockIdx.x * 256 + threadIdx.x) >> 6;
    int lane = threadIdx.x & 63;
    if (gw >= NN) return;
    u32 hv = *(const u32*)(h + (size_t)gw * 128 + lane * 2);
    u32 wv = *(const u32*)(w3 + lane * 2);
    float s = b2f((u16)(hv & 0xffff)) * b2f((u16)(wv & 0xffff)) +
              b2f((u16)(hv >> 16)) * b2f((u16)(wv >> 16));
    for (int off = 32; off; off >>= 1) s += __shfl_down(s, off);
    if (lane == 0) out[gw] = s + b2f(b3[0]);
}

extern "C" void kernel_launch(void* const* d_in, const int* in_sizes, int n_in,
                              void* d_out, int out_size, void* d_ws, size_t ws_size,
                              hipStream_t stream) {
    (void)in_sizes; (void)n_in; (void)out_size; (void)ws_size;
    const float* x  = (const float*)d_in[0];
    const int*   ei = (const int*)d_in[1];
    float* out = (float*)d_out;

    char* p = (char*)d_ws;
    auto alloc = [&](size_t bytes) { char* q = p; p += (bytes + 255) & ~(size_t)255; return q; };
    int*   cnt    = (int*)alloc(NN * 4);
    int*   rowptr = (int*)alloc((NN + 1) * 4);
    int*   cursor = (int*)alloc(NN * 4);
    float* dinv   = (float*)alloc(NN * 4);
    int*   cols   = (int*)alloc(EE * 4);
    float* vals   = (float*)alloc(EE * 4);
    u16*   xp     = (u16*)alloc((size_t)MPAD * 96 * 2);
    u16*   wbuf   = (u16*)alloc((size_t)2678784 * 2);
    u16*   smallC = (u16*)alloc(10240 * 2);
    u16*   S1     = (u16*)alloc((size_t)MPAD * 256 * 2);
    u16*   S2     = (u16*)alloc((size_t)MPAD * 256 * 2);
    u16*   S3     = (u16*)alloc((size_t)MPAD * 256 * 2);
    u16*   S4     = (u16*)alloc((size_t)MPAD * 256 * 2);
    u16*   Zb     = (u16*)alloc((size_t)MPAD * 768 * 2);
    u16*   Y2     = (u16*)alloc((size_t)MPAD * 512 * 2);
    u16*   Y3     = (u16*)alloc((size_t)MPAD * 256 * 2);
    u16*   bufA   = (u16*)alloc((size_t)MPAD * 1024 * 2);
    u16*   concat = (u16*)alloc((size_t)MPAD * 1024 * 2);

    u16* winT  = wbuf;             // [256][96]
    u16* w0T   = wbuf + 24576;     // [4][256][256]
    u16* w12T  = wbuf + 286720;    // [8][256][1024]
    u16* w1T   = wbuf + 2383872;   // [256][1024]
    u16* w2T   = wbuf + 2646016;   // [128][256]
    u16* binC  = smallC;
    u16* mb0C  = smallC + 256;
    u16* mb12C = smallC + 1280;
    u16* lngC  = smallC + 3328;
    u16* lnbC  = smallC + 6400;
    u16* b1C   = smallC + 9472;
    u16* b2C   = smallC + 9728;
    u16* w3C   = smallC + 9856;
    u16* b3C   = smallC + 9984;

    const int* srcA = ei;
    const int* dstA = ei + EE;

    hipMemsetAsync(cnt, 0, NN * 4, stream);

    k_padx<<<(MPAD * 96 + 255) / 256, 256, 0, stream>>>(x, xp);
    TT t0{(const float*)d_in[2],  winT, 84,   256, 96};
    TT t1{(const float*)d_in[4],  w0T,  256,  256, 256};    // B=4 via block range (64 tiles)
    TT t2{(const float*)d_in[6],  w12T, 1024, 256, 1024};   // B=8 (512 tiles)
    TT t3{(const float*)d_in[10], w1T,  1024, 256, 1024};
    TT t4{(const float*)d_in[12], w2T,  256,  128, 256};
    k_transT<<<656, 256, 0, stream>>>(t0, t1, t2, t3, t4);
    CvtSrcs CS{(const float*)d_in[3], (const float*)d_in[5], (const float*)d_in[7],
               (const float*)d_in[8], (const float*)d_in[9], (const float*)d_in[11],
               (const float*)d_in[13], (const float*)d_in[14], (const float*)d_in[15]};
    k_cvt_all<<<40, 256, 0, stream>>>(CS, smallC);

    k_count<<<(EE + 255) / 256, 256, 0, stream>>>(dstA, cnt);
    k_scan<<<1, 256, 0, stream>>>(cnt, rowptr, cursor, dinv);
    k_fill<<<(EE + 255) / 256, 256, 0, stream>>>(srcA, dstA, cursor, cols, vals, dinv);

    auto gx = [](int nbm, int nbn) { return 8 * ((nbm + 7) / 8) * nbn; };

    // input GEMM: S1 = gelu(xp @ winT^T + b_in)  [MPAD,256], K=96, 128x64 tiles
    k_gemm<128, 64, 1, 0, 0><<<gx(79, 4), 256, 0, stream>>>(xp, xp, xp, xp, winT, binC, S1, nullptr, 96, 256, 0, 79, 4);

    // ---- layer 0: prop chain then batched GEMM ----
    k_propw<0><<<2500, 256, 0, stream>>>(S1, 256, 1, rowptr, cols, vals, dinv, nullptr, nullptr, 0, S2);
    k_propw<0><<<2500, 256, 0, stream>>>(S2, 256, 1, rowptr, cols, vals, dinv, nullptr, nullptr, 0, S3);
    k_propw<0><<<2500, 256, 0, stream>>>(S3, 256, 1, rowptr, cols, vals, dinv, nullptr, nullptr, 0, S4);
    k_gemm<128, 64, 0, 0, 1><<<dim3(gx(79, 4), 4), 256, 0, stream>>>(S1, S2, S3, S4, w0T, mb0C, concat, nullptr, 256, 1024, 0, 79, 4);
    k_ln_gelu<<<NN, 256, 0, stream>>>(concat, lngC, lnbC, bufA);

    // ---- layers 1,2: merged GEMM (N=1024, 128x64 tiles) + shared prop chain ----
    for (int L = 0; L < 2; L++) {
        const u16* WT = w12T + (size_t)L * 1024 * 1024;
        const u16* BB = mb12C + L * 1024;
        k_gemm<128, 64, 0, 2, 0><<<gx(79, 16), 256, 0, stream>>>(bufA, bufA, bufA, bufA, WT, BB, concat, Zb, 1024, 0, 0, 79, 16);
        k_propw<1><<<7500, 256, 0, stream>>>(Zb, 768, 3, rowptr, cols, vals, dinv, concat, BB + 256, 256, Y2);
        k_propw<1><<<5000, 256, 0, stream>>>(Y2, 512, 2, rowptr, cols, vals, dinv, concat, BB + 512, 512, Y3);
        k_propw<1><<<2500, 256, 0, stream>>>(Y3, 256, 1, rowptr, cols, vals, dinv, concat, BB + 768, 768, Y3);
        k_ln_gelu<<<NN, 256, 0, stream>>>(concat, lngC + (L + 1) * 1024, lnbC + (L + 1) * 1024, bufA);
    }

    // ---- final MLP (64x64 tiles for small-N shapes) ----
    k_gemm<64, 64, 1, 0, 0><<<gx(158, 4), 256, 0, stream>>>(bufA, bufA, bufA, bufA, w1T, b1C, S1, nullptr, 1024, 256, 0, 158, 4);
    k_gemm<64, 64, 1, 0, 0><<<gx(158, 2), 256, 0, stream>>>(S1, S1, S1, S1, w2T, b2C, S2, nullptr, 256, 128, 0, 158, 2);
    k_final<<<2500, 256, 0, stream>>>(S2, w3C, b3C, out);
}

// Round 8
// 505.231 us; speedup vs baseline: 1.5202x; 1.0288x over previous
//
#include <hip/hip_runtime.h>

typedef unsigned short u16;
typedef unsigned int u32;
typedef __bf16 bf16x8 __attribute__((ext_vector_type(8)));
typedef float f32x4 __attribute__((ext_vector_type(4)));

#define NN 10000
#define EE 160000
#define MPAD 10112   // 79 * 128 = 158 * 64

__device__ inline float b2f(u16 u) { return __uint_as_float(((u32)u) << 16); }
__device__ inline u16 f2b(float f) {
    u32 u = __float_as_uint(f);
    return (u16)((u + 0x7fffu + ((u >> 16) & 1u)) >> 16);   // RNE
}
__device__ inline float gelu_f(float x) {
    return 0.5f * x * (1.0f + erff(x * 0.70710678118654752f));
}
__device__ inline void load_lds16(const u16* g, u16* l) {
    __builtin_amdgcn_global_load_lds((const __attribute__((address_space(1))) u32*)g,
                                     (__attribute__((address_space(3))) u32*)l, 16, 0, 0);
}

// ---------------- CSR build ----------------
__global__ __launch_bounds__(256) void k_count(const int* __restrict__ dst, int* __restrict__ cnt) {
    int e = blockIdx.x * 256 + threadIdx.x;
    if (e < EE) atomicAdd(&cnt[dst[e]], 1);
}

__global__ __launch_bounds__(256) void k_scan(const int* __restrict__ cnt, int* __restrict__ rowptr,
                                              int* __restrict__ cursor, float* __restrict__ dinv) {
    __shared__ int part[256];
    const int t = threadIdx.x;
    const int CH = 40;
    int base = t * CH;
    int ssum = 0;
    for (int k = 0; k < CH; k++) { int i = base + k; if (i < NN) ssum += cnt[i]; }
    part[t] = ssum;
    __syncthreads();
    for (int off = 1; off < 256; off <<= 1) {
        int v = (t >= off) ? part[t - off] : 0;
        __syncthreads();
        part[t] += v;
        __syncthreads();
    }
    int run = part[t] - ssum;
    for (int k = 0; k < CH; k++) {
        int i = base + k;
        if (i < NN) {
            rowptr[i] = run; cursor[i] = run;
            int c = cnt[i];
            dinv[i] = rsqrtf((float)(c + 1));
            run += c;
        }
    }
    if (t == 255) rowptr[NN] = run;
}

__global__ __launch_bounds__(256) void k_fill(const int* __restrict__ src, const int* __restrict__ dst,
                                              int* __restrict__ cursor, int* __restrict__ cols,
                                              float* __restrict__ vals, const float* __restrict__ dinv) {
    int e = blockIdx.x * 256 + threadIdx.x;
    if (e < EE) {
        int s = src[e], d = dst[e];
        int pos = atomicAdd(&cursor[d], 1);
        cols[pos] = s;
        vals[pos] = dinv[s] * dinv[d];
    }
}

// ---------------- ingest ----------------
__global__ __launch_bounds__(256) void k_padx(const float* __restrict__ x, u16* __restrict__ xp) {
    int idx = blockIdx.x * 256 + threadIdx.x;
    if (idx >= MPAD * 96) return;
    int r = idx / 96, c = idx - r * 96;
    u16 v = 0;
    if (r < NN && c < 84) v = f2b(x[(size_t)r * 84 + c]);
    xp[idx] = v;
}

// LDS-tiled transpose: src [B][K][Nc] f32 -> dst [B][Nc][Kp] bf16 (zero-pad k>=K)
struct TT { const float* src; u16* dst; int K, Nc, Kp; };
__global__ __launch_bounds__(256) void k_transT(TT t0, TT t1, TT t2, TT t3, TT t4) {
    int b = blockIdx.x; TT T;
    if (b < 8)        { T = t0; }
    else if (b < 72)  { T = t1; b -= 8; }
    else if (b < 584) { T = t2; b -= 72; }
    else if (b < 648) { T = t3; b -= 584; }
    else              { T = t4; b -= 648; }
    int tk = (T.K + 63) >> 6, tn = T.Nc >> 6;
    int bb  = b / (tk * tn);
    int rem = b - bb * (tk * tn);
    int k0 = (rem / tn) * 64, n0 = (rem % tn) * 64;
    __shared__ u16 tile[64][65];
    const float* src = T.src + (size_t)bb * T.K * T.Nc;
    u16* dst = T.dst + (size_t)bb * T.Nc * T.Kp;
    int c = threadIdx.x & 63, r0 = threadIdx.x >> 6;
#pragma unroll
    for (int i = 0; i < 16; i++) {
        int r = r0 + i * 4;
        int k = k0 + r;
        u16 v = 0;
        if (k < T.K) v = f2b(src[(size_t)k * T.Nc + n0 + c]);
        tile[r][c] = v;
    }
    __syncthreads();
    int rr = threadIdx.x & 63, cc0 = threadIdx.x >> 6;
#pragma unroll
    for (int i = 0; i < 16; i++) {
        int cc = cc0 + i * 4;
        int k = k0 + rr;
        if (k < T.Kp) dst[(size_t)(n0 + cc) * T.Kp + k] = tile[rr][cc];
    }
}

struct CvtSrcs { const float *b_in, *mh_b0, *mh_b12, *ln_g, *ln_b, *b1, *b2, *w3, *b3; };
__global__ __launch_bounds__(256) void k_cvt_all(CvtSrcs S, u16* __restrict__ dst) {
    int i = blockIdx.x * 256 + threadIdx.x;
    const float* s; int base;
    if (i < 256)       { s = S.b_in;   base = 0; }
    else if (i < 1280) { s = S.mh_b0;  base = 256; }
    else if (i < 3328) { s = S.mh_b12; base = 1280; }
    else if (i < 6400) { s = S.ln_g;   base = 3328; }
    else if (i < 9472) { s = S.ln_b;   base = 6400; }
    else if (i < 9728) { s = S.b1;     base = 9472; }
    else if (i < 9856) { s = S.b2;     base = 9728; }
    else if (i < 9984) { s = S.w3;     base = 9856; }
    else if (i < 9985) { s = S.b3;     base = 9984; }
    else return;
    dst[i] = f2b(s[i - base]);
}

// ---------------- templated MFMA GEMM, double-buffered DMA pipeline ----------------
// One __syncthreads per K-iter: barrier drains the DMA issued LAST iter (buf cur),
// then this iter's DMA (buf nxt) is issued and stays in flight through the MFMAs.
// XCD-swizzled 1D grid (see round 6). EPI/BATCH semantics unchanged.
template<int TM, int TN, int ACT, int EPI, int BATCH>
__global__ __launch_bounds__(256) void k_gemm(const u16* __restrict__ A0, const u16* __restrict__ A1,
                                              const u16* __restrict__ A2, const u16* __restrict__ A3,
                                              const u16* __restrict__ Bt, const u16* __restrict__ bias,
                                              u16* __restrict__ C, u16* __restrict__ Z,
                                              int K, int ldc, int col0, int NB_M, int NB_N) {
    constexpr int AM = TM / 32, AN = TN / 32;       // per-wave 16x16 tiles
    constexpr int CA = TM / 16, CB = TN / 16;       // 16-row staging chunks
    constexpr int NCH = (CA + CB) / 4;              // chunks per wave
    __shared__ __align__(16) u16 As[2][TM * 32];
    __shared__ __align__(16) u16 Bs[2][TN * 32];
    int id = blockIdx.x;
    int g8 = id & 7, sIdx = id >> 3;
    int nb = sIdx % NB_N, jb = sIdx / NB_N;
    int mb = g8 + 8 * jb;
    if (mb >= NB_M) return;
    const u16* A = A0;
    if (BATCH) {
        int z = blockIdx.y;
        if (z == 1) A = A1; else if (z == 2) A = A2; else if (z == 3) A = A3;
        Bt   += (size_t)z * 256 * K;
        bias += z * 256;
        col0 += z * 256;
    }
    const int t = threadIdx.x;
    const int wv = t >> 6, lane = t & 63;
    const int wm = wv >> 1, wn = wv & 1;
    const int quad = lane >> 4, l16 = lane & 15;
    const int tileM = mb * TM, tileN = nb * TN;

    f32x4 acc[AM][AN] = {};

    const int rch = lane >> 2, c8 = (lane & 3) * 8;
    const u16* gsrc[NCH];
    u16* l0[NCH]; u16* l1[NCH];
#pragma unroll
    for (int i = 0; i < NCH; i++) {
        int c = wv + 4 * i;
        if (c < CA) {
            gsrc[i] = A + (size_t)(tileM + c * 16 + rch) * K + c8;
            l0[i] = &As[0][c * 512 + lane * 8];
            l1[i] = &As[1][c * 512 + lane * 8];
        } else {
            int cc = c - CA;
            gsrc[i] = Bt + (size_t)(tileN + cc * 16 + rch) * K + c8;
            l0[i] = &Bs[0][cc * 512 + lane * 8];
            l1[i] = &Bs[1][cc * 512 + lane * 8];
        }
    }

    // prologue: stage k0=0 into buffer 0
#pragma unroll
    for (int i = 0; i < NCH; i++) load_lds16(gsrc[i], l0[i]);

    int kb = 0;
    for (int k0 = 0; k0 < K; k0 += 32, kb ^= 1) {
        __syncthreads();                      // drains DMA for buf kb; frees buf kb^1
        if (k0 + 32 < K) {
#pragma unroll
            for (int i = 0; i < NCH; i++)
                load_lds16(gsrc[i] + k0 + 32, kb ? l0[i] : l1[i]);
        }
        const u16* Ab = As[kb];
        const u16* Bb = Bs[kb];
        bf16x8 af[AM], bfr[AN];
#pragma unroll
        for (int tm = 0; tm < AM; tm++)
            af[tm] = *(const bf16x8*)&Ab[(wm * (TM / 2) + tm * 16 + l16) * 32 + quad * 8];
#pragma unroll
        for (int tn = 0; tn < AN; tn++)
            bfr[tn] = *(const bf16x8*)&Bb[(wn * (TN / 2) + tn * 16 + l16) * 32 + quad * 8];
#pragma unroll
        for (int tm = 0; tm < AM; tm++)
#pragma unroll
            for (int tn = 0; tn < AN; tn++)
                acc[tm][tn] = __builtin_amdgcn_mfma_f32_16x16x32_bf16(af[tm], bfr[tn], acc[tm][tn], 0, 0, 0);
    }

#pragma unroll
    for (int tm = 0; tm < AM; tm++)
#pragma unroll
        for (int tn = 0; tn < AN; tn++)
#pragma unroll
            for (int r = 0; r < 4; r++) {
                int row = tileM + wm * (TM / 2) + tm * 16 + quad * 4 + r;
                int col = tileN + wn * (TN / 2) + tn * 16 + l16;
                float v = acc[tm][tn][r];
                if (EPI == 2) {
                    if (col < 256) C[(size_t)row * 1024 + col] = f2b(v + b2f(bias[col]));
                    else           Z[(size_t)row * 768 + (col - 256)] = f2b(v);
                } else {
                    v += b2f(bias[col]);
                    if (ACT) v = gelu_f(v);
                    C[(size_t)row * ldc + col0 + col] = f2b(v);
                }
            }
}

// ---------------- wide propagation (4 rows in flight per half-wave) ----------------
template<int CAT0>
__global__ __launch_bounds__(256) void k_propw(const u16* __restrict__ hin, int W, int G,
                                               const int* __restrict__ rowptr, const int* __restrict__ cols,
                                               const float* __restrict__ vals, const float* __restrict__ dinv,
                                               u16* __restrict__ concat, const u16* __restrict__ bias,
                                               int col0, u16* __restrict__ out2) {
    int unit = blockIdx.x * 4 + (threadIdx.x >> 6);
    if (unit >= NN * G) return;
    int node = unit / G, g = unit - node * G;
    int lane = threadIdx.x & 63;
    int half = lane >> 5, fl = lane & 31;
    const u16* base = hin + g * 256 + fl * 8;
    float a0 = 0, a1 = 0, a2 = 0, a3 = 0, a4 = 0, a5 = 0, a6 = 0, a7 = 0;
    if (half == 1) {   // self-loop on the upper half (balances work)
        float di = dinv[node], sw = di * di;
        bf16x8 sv = *(const bf16x8*)(base + (size_t)node * W);
        a0 = sw * (float)sv[0]; a1 = sw * (float)sv[1]; a2 = sw * (float)sv[2]; a3 = sw * (float)sv[3];
        a4 = sw * (float)sv[4]; a5 = sw * (float)sv[5]; a6 = sw * (float)sv[6]; a7 = sw * (float)sv[7];
    }
    int s = rowptr[node], e = rowptr[node + 1];
    int q = s + half;
    for (; q + 6 < e; q += 8) {     // 4 rows in flight per half-wave
        int j0 = cols[q], j1 = cols[q + 2], j2 = cols[q + 4], j3 = cols[q + 6];
        float w0 = vals[q], w1 = vals[q + 2], w2 = vals[q + 4], w3 = vals[q + 6];
        bf16x8 v0 = *(const bf16x8*)(base + (size_t)j0 * W);
        bf16x8 v1 = *(const bf16x8*)(base + (size_t)j1 * W);
        bf16x8 v2 = *(const bf16x8*)(base + (size_t)j2 * W);
        bf16x8 v3 = *(const bf16x8*)(base + (size_t)j3 * W);
        a0 += w0 * (float)v0[0] + w1 * (float)v1[0] + w2 * (float)v2[0] + w3 * (float)v3[0];
        a1 += w0 * (float)v0[1] + w1 * (float)v1[1] + w2 * (float)v2[1] + w3 * (float)v3[1];
        a2 += w0 * (float)v0[2] + w1 * (float)v1[2] + w2 * (float)v2[2] + w3 * (float)v3[2];
        a3 += w0 * (float)v0[3] + w1 * (float)v1[3] + w2 * (float)v2[3] + w3 * (float)v3[3];
        a4 += w0 * (float)v0[4] + w1 * (float)v1[4] + w2 * (float)v2[4] + w3 * (float)v3[4];
        a5 += w0 * (float)v0[5] + w1 * (float)v1[5] + w2 * (float)v2[5] + w3 * (float)v3[5];
        a6 += w0 * (float)v0[6] + w1 * (float)v1[6] + w2 * (float)v2[6] + w3 * (float)v3[6];
        a7 += w0 * (float)v0[7] + w1 * (float)v1[7] + w2 * (float)v2[7] + w3 * (float)v3[7];
    }
    for (; q + 2 < e; q += 4) {     // 2 rows in flight
        int j0 = cols[q], j1 = cols[q + 2];
        float w0 = vals[q], w1 = vals[q + 2];
        bf16x8 v0 = *(const bf16x8*)(base + (size_t)j0 * W);
        bf16x8 v1 = *(const bf16x8*)(base + (size_t)j1 * W);
        a0 += w0 * (float)v0[0] + w1 * (float)v1[0];
        a1 += w0 * (float)v0[1] + w1 * (float)v1[1];
        a2 += w0 * (float)v0[2] + w1 * (float)v1[2];
        a3 += w0 * (float)v0[3] + w1 * (float)v1[3];
        a4 += w0 * (float)v0[4] + w1 * (float)v1[4];
        a5 += w0 * (float)v0[5] + w1 * (float)v1[5];
        a6 += w0 * (float)v0[6] + w1 * (float)v1[6];
        a7 += w0 * (float)v0[7] + w1 * (float)v1[7];
    }
    if (q < e) {
        int j = cols[q];
        float w = vals[q];
        bf16x8 v = *(const bf16x8*)(base + (size_t)j * W);
        a0 += w * (float)v[0]; a1 += w * (float)v[1]; a2 += w * (float)v[2]; a3 += w * (float)v[3];
        a4 += w * (float)v[4]; a5 += w * (float)v[5]; a6 += w * (float)v[6]; a7 += w * (float)v[7];
    }
    a0 += __shfl_down(a0, 32); a1 += __shfl_down(a1, 32);
    a2 += __shfl_down(a2, 32); a3 += __shfl_down(a3, 32);
    a4 += __shfl_down(a4, 32); a5 += __shfl_down(a5, 32);
    a6 += __shfl_down(a6, 32); a7 += __shfl_down(a7, 32);
    if (half == 0) {
        int f = fl * 8;
        union { u16 u[8]; uint4 v; } pk;
        if (CAT0 && g == 0) {
            pk.u[0] = f2b(a0 + b2f(bias[f + 0])); pk.u[1] = f2b(a1 + b2f(bias[f + 1]));
            pk.u[2] = f2b(a2 + b2f(bias[f + 2])); pk.u[3] = f2b(a3 + b2f(bias[f + 3]));
            pk.u[4] = f2b(a4 + b2f(bias[f + 4])); pk.u[5] = f2b(a5 + b2f(bias[f + 5]));
            pk.u[6] = f2b(a6 + b2f(bias[f + 6])); pk.u[7] = f2b(a7 + b2f(bias[f + 7]));
            *(uint4*)(concat + (size_t)node * 1024 + col0 + f) = pk.v;
        } else {
            int W2 = W - CAT0 * 256;
            pk.u[0] = f2b(a0); pk.u[1] = f2b(a1); pk.u[2] = f2b(a2); pk.u[3] = f2b(a3);
            pk.u[4] = f2b(a4); pk.u[5] = f2b(a5); pk.u[6] = f2b(a6); pk.u[7] = f2b(a7);
            *(uint4*)(out2 + (size_t)node * W2 + (g - CAT0) * 256 + f) = pk.v;
        }
    }
}

// ---------------- LayerNorm(1024) + gelu, bf16 in -> bf16 out ----------------
__global__ __launch_bounds__(256) void k_ln_gelu(const u16* __restrict__ X, const u16* __restrict__ g,
                                                 const u16* __restrict__ b, u16* __restrict__ out) {
    __shared__ float red[256];
    const int row = blockIdx.x, t = threadIdx.x;
    ushort4 xv = *(const ushort4*)(X + (size_t)row * 1024 + t * 4);
    float x0 = b2f(xv.x), x1 = b2f(xv.y), x2 = b2f(xv.z), x3 = b2f(xv.w);
    red[t] = x0 + x1 + x2 + x3;
    __syncthreads();
    for (int off = 128; off; off >>= 1) {
        if (t < off) red[t] += red[t + off];
        __syncthreads();
    }
    float mu = red[0] * (1.f / 1024.f);
    __syncthreads();
    float d0 = x0 - mu, d1 = x1 - mu, d2 = x2 - mu, d3 = x3 - mu;
    red[t] = d0 * d0 + d1 * d1 + d2 * d2 + d3 * d3;
    __syncthreads();
    for (int off = 128; off; off >>= 1) {
        if (t < off) red[t] += red[t + off];
        __syncthreads();
    }
    float rs = rsqrtf(red[0] * (1.f / 1024.f) + 1e-5f);
    int c = t * 4;
    ushort4 gv = *(const ushort4*)(g + c);
    ushort4 bv = *(const ushort4*)(b + c);
    ushort4 o;
    o.x = f2b(gelu_f(d0 * rs * b2f(gv.x) + b2f(bv.x)));
    o.y = f2b(gelu_f(d1 * rs * b2f(gv.y) + b2f(bv.y)));
    o.z = f2b(gelu_f(d2 * rs * b2f(gv.z) + b2f(bv.z)));
    o.w = f2b(gelu_f(d3 * rs * b2f(gv.w) + b2f(bv.w)));
    *(ushort4*)(out + (size_t)row * 1024 + c) = o;
}

// ---------------- final dot: out[i] = h[i,0:128] . w3 + b3  (f32 out) --------
__global__ __launch_bounds__(256) void k_final(const u16* __restrict__ h, const u16* __restrict__ w3,
                                               const u16* __restrict__ b3, float* __restrict__ out) {
    int gw = (blockIdx.x * 256 + threadIdx.x) >> 6;
    int lane = threadIdx.x & 63;
    if (gw >= NN) return;
    u32 hv = *(const u32*)(h + (size_t)gw * 128 + lane * 2);
    u32 wv = *(const u32*)(w3 + lane * 2);
    float s = b2f((u16)(hv & 0xffff)) * b2f((u16)(wv & 0xffff)) +
              b2f((u16)(hv >> 16)) * b2f((u16)(wv >> 16));
    for (int off = 32; off; off >>= 1) s += __shfl_down(s, off);
    if (lane == 0) out[gw] = s + b2f(b3[0]);
}

extern "C" void kernel_launch(void* const* d_in, const int* in_sizes, int n_in,
                              void* d_out, int out_size, void* d_ws, size_t ws_size,
                              hipStream_t stream) {
    (void)in_sizes; (void)n_in; (void)out_size; (void)ws_size;
    const float* x  = (const float*)d_in[0];
    const int*   ei = (const int*)d_in[1];
    float* out = (float*)d_out;

    char* p = (char*)d_ws;
    auto alloc = [&](size_t bytes) { char* q = p; p += (bytes + 255) & ~(size_t)255; return q; };
    int*   cnt    = (int*)alloc(NN * 4);
    int*   rowptr = (int*)alloc((NN + 1) * 4);
    int*   cursor = (int*)alloc(NN * 4);
    float* dinv   = (float*)alloc(NN * 4);
    int*   cols   = (int*)alloc(EE * 4);
    float* vals   = (float*)alloc(EE * 4);
    u16*   xp     = (u16*)alloc((size_t)MPAD * 96 * 2);
    u16*   wbuf   = (u16*)alloc((size_t)2678784 * 2);
    u16*   smallC = (u16*)alloc(10240 * 2);
    u16*   S1     = (u16*)alloc((size_t)MPAD * 256 * 2);
    u16*   S2     = (u16*)alloc((size_t)MPAD * 256 * 2);
    u16*   S3     = (u16*)alloc((size_t)MPAD * 256 * 2);
    u16*   S4     = (u16*)alloc((size_t)MPAD * 256 * 2);
    u16*   Zb     = (u16*)alloc((size_t)MPAD * 768 * 2);
    u16*   Y2     = (u16*)alloc((size_t)MPAD * 512 * 2);
    u16*   Y3     = (u16*)alloc((size_t)MPAD * 256 * 2);
    u16*   bufA   = (u16*)alloc((size_t)MPAD * 1024 * 2);
    u16*   concat = (u16*)alloc((size_t)MPAD * 1024 * 2);

    u16* winT  = wbuf;             // [256][96]
    u16* w0T   = wbuf + 24576;     // [4][256][256]
    u16* w12T  = wbuf + 286720;    // [8][256][1024]
    u16* w1T   = wbuf + 2383872;   // [256][1024]
    u16* w2T   = wbuf + 2646016;   // [128][256]
    u16* binC  = smallC;
    u16* mb0C  = smallC + 256;
    u16* mb12C = smallC + 1280;
    u16* lngC  = smallC + 3328;
    u16* lnbC  = smallC + 6400;
    u16* b1C   = smallC + 9472;
    u16* b2C   = smallC + 9728;
    u16* w3C   = smallC + 9856;
    u16* b3C   = smallC + 9984;

    const int* srcA = ei;
    const int* dstA = ei + EE;

    hipMemsetAsync(cnt, 0, NN * 4, stream);

    k_padx<<<(MPAD * 96 + 255) / 256, 256, 0, stream>>>(x, xp);
    TT t0{(const float*)d_in[2],  winT, 84,   256, 96};
    TT t1{(const float*)d_in[4],  w0T,  256,  256, 256};
    TT t2{(const float*)d_in[6],  w12T, 1024, 256, 1024};
    TT t3{(const float*)d_in[10], w1T,  1024, 256, 1024};
    TT t4{(const float*)d_in[12], w2T,  256,  128, 256};
    k_transT<<<656, 256, 0, stream>>>(t0, t1, t2, t3, t4);
    CvtSrcs CS{(const float*)d_in[3], (const float*)d_in[5], (const float*)d_in[7],
               (const float*)d_in[8], (const float*)d_in[9], (const float*)d_in[11],
               (const float*)d_in[13], (const float*)d_in[14], (const float*)d_in[15]};
    k_cvt_all<<<40, 256, 0, stream>>>(CS, smallC);

    k_count<<<(EE + 255) / 256, 256, 0, stream>>>(dstA, cnt);
    k_scan<<<1, 256, 0, stream>>>(cnt, rowptr, cursor, dinv);
    k_fill<<<(EE + 255) / 256, 256, 0, stream>>>(srcA, dstA, cursor, cols, vals, dinv);

    auto gx = [](int nbm, int nbn) { return 8 * ((nbm + 7) / 8) * nbn; };

    // input GEMM: S1 = gelu(xp @ winT^T + b_in)  [MPAD,256], K=96, 128x64 tiles
    k_gemm<128, 64, 1, 0, 0><<<gx(79, 4), 256, 0, stream>>>(xp, xp, xp, xp, winT, binC, S1, nullptr, 96, 256, 0, 79, 4);

    // ---- layer 0: prop chain then batched GEMM ----
    k_propw<0><<<2500, 256, 0, stream>>>(S1, 256, 1, rowptr, cols, vals, dinv, nullptr, nullptr, 0, S2);
    k_propw<0><<<2500, 256, 0, stream>>>(S2, 256, 1, rowptr, cols, vals, dinv, nullptr, nullptr, 0, S3);
    k_propw<0><<<2500, 256, 0, stream>>>(S3, 256, 1, rowptr, cols, vals, dinv, nullptr, nullptr, 0, S4);
    k_gemm<128, 64, 0, 0, 1><<<dim3(gx(79, 4), 4), 256, 0, stream>>>(S1, S2, S3, S4, w0T, mb0C, concat, nullptr, 256, 1024, 0, 79, 4);
    k_ln_gelu<<<NN, 256, 0, stream>>>(concat, lngC, lnbC, bufA);

    // ---- layers 1,2: merged GEMM (N=1024, 128x64 tiles) + shared prop chain ----
    for (int L = 0; L < 2; L++) {
        const u16* WT = w12T + (size_t)L * 1024 * 1024;
        const u16* BB = mb12C + L * 1024;
        k_gemm<128, 64, 0, 2, 0><<<gx(79, 16), 256, 0, stream>>>(bufA, bufA, bufA, bufA, WT, BB, concat, Zb, 1024, 0, 0, 79, 16);
        k_propw<1><<<7500, 256, 0, stream>>>(Zb, 768, 3, rowptr, cols, vals, dinv, concat, BB + 256, 256, Y2);
        k_propw<1><<<5000, 256, 0, stream>>>(Y2, 512, 2, rowptr, cols, vals, dinv, concat, BB + 512, 512, Y3);
        k_propw<1><<<2500, 256, 0, stream>>>(Y3, 256, 1, rowptr, cols, vals, dinv, concat, BB + 768, 768, Y3);
        k_ln_gelu<<<NN, 256, 0, stream>>>(concat, lngC + (L + 1) * 1024, lnbC + (L + 1) * 1024, bufA);
    }

    // ---- final MLP (64x64 tiles) ----
    k_gemm<64, 64, 1, 0, 0><<<gx(158, 4), 256, 0, stream>>>(bufA, bufA, bufA, bufA, w1T, b1C, S1, nullptr, 1024, 256, 0, 158, 4);
    k_gemm<64, 64, 1, 0, 0><<<gx(158, 2), 256, 0, stream>>>(S1, S1, S1, S1, w2T, b2C, S2, nullptr, 256, 128, 0, 158, 2);
    k_final<<<2500, 256, 0, stream>>>(S2, w3C, b3C, out);
}